// Round 15
// baseline (648.344 us; speedup 1.0000x reference)
//
#include <hip/hip_runtime.h>
#include <hip/hip_bf16.h>

typedef __hip_bfloat16 bf16;
typedef __attribute__((ext_vector_type(8))) short short8;
typedef __attribute__((ext_vector_type(4))) short bfx4;
typedef __attribute__((ext_vector_type(4))) float f32x4;

#define DEV __device__ __forceinline__

static constexpr int NSUP = 40;    // B*N_WAY*K_SHOT
static constexpr int NQRY = 120;   // B*Q
static constexpr int NIMG = 160;
static constexpr int GM   = 48600; // 600 * 81 rows of the g-MLP
static constexpr int GMP  = 48640; // padded to 380*128
static constexpr int NBS  = 128;   // stats blocks for support group
static constexpr int NBQ  = 384;   // stats blocks for query group

DEV float b2f(short s) {
    union { unsigned int u; float f; } v; v.u = ((unsigned int)(unsigned short)s) << 16; return v.f;
}
DEV short bfbits(float v) {
    bf16 h = __float2bfloat16(v);
    union { bf16 b; short s; } u; u.b = h; return u.s;
}

// bijective XCD swizzle (m204)
DEV int xcd_swz(int b, int nwg) {
    int q = nwg >> 3, r = nwg & 7;
    int x = b & 7, i = b >> 3;
    return (x < r) ? x * (q + 1) + i : r * (q + 1) + (x - r) * q + i;
}

#define GLL(gp, lp) __builtin_amdgcn_global_load_lds( \
    (const __attribute__((address_space(1))) void*)(gp), \
    (__attribute__((address_space(3))) void*)(lp), 16, 0, 0)

// ---------------- fused prep: input->NHWC4 + all weight transforms + counter zero
__global__ void prep_kernel(const float* sx, const float* qx, bf16* img,
                            const float* cw1, const float* cw2, const float* cw3,
                            const float* cw4, const float* gW2, const float* gW3,
                            const float* gW4, const float* fW1, const float* fW2,
                            const float* fW3, const float* fW4, const float* fb4,
                            bf16* Wc1, bf16* Wp, bf16* WTg, bf16* fWT, float* fb4p,
                            int* counters) {
    long gid = (long)blockIdx.x * 256 + threadIdx.x;
    if (gid < 8) counters[gid] = 0;
    if (gid < (long)NIMG * 7056) {
        int n = (int)(gid / 7056), p = (int)(gid % 7056);
        const float* im = ((n < NSUP) ? sx + (size_t)n * 3 * 7056
                                      : qx + (size_t)(n - NSUP) * 3 * 7056) + p;
        bfx4 o;
        o[0] = bfbits(im[0]);
        o[1] = bfbits(im[7056]);
        o[2] = bfbits(im[14112]);
        o[3] = 0;
        *(bfx4*)&img[gid * 4] = o;
        return;
    }
    int idx = (int)(gid - (long)NIMG * 7056);
    if (idx < 4096) {
        int oc = idx >> 6, k = idx & 63;
        int ky = k >> 4, r = k & 15;
        float v = 0.f;
        if (ky < 3 && r < 12) {
            int kx = r >> 2, ic = r & 3;
            if (ic < 3) v = cw1[oc * 27 + ic * 9 + ky * 3 + kx];
        }
        Wc1[idx] = __float2bfloat16(v);
        return;
    }
    idx -= 4096;
    if (idx < 3 * 64 * 584) {
        int L = idx / (64 * 584), r = idx % (64 * 584);
        int oc = r / 584, kk = r % 584;
        const float* src = (L == 0) ? cw2 : (L == 1) ? cw3 : cw4;
        float v = 0.f;
        if (kk < 576) {
            int ic = kk & 63, tap = kk >> 6;
            v = src[oc * 576 + ic * 9 + tap];
        }
        Wp[idx] = __float2bfloat16(v);
        return;
    }
    idx -= 3 * 64 * 584;
    if (idx < 3 * 65536) {
        int L = idx >> 16, r = idx & 65535, n = r >> 8, k = r & 255;
        const float* W = (L == 0) ? gW2 : (L == 1) ? gW3 : gW4;
        WTg[idx] = __float2bfloat16(W[k * 256 + n]);
        return;
    }
    idx -= 3 * 65536;
    if (idx < 65536) {
        int n = idx >> 8, k = idx & 255;
        fWT[idx] = __float2bfloat16(fW1[k * 256 + n]);
    } else if (idx < 131072) {
        int r = idx - 65536, n = r >> 8, k = r & 255;
        fWT[idx] = __float2bfloat16(fW2[k * 256 + n]);
    } else if (idx < 163840) {
        int r = idx - 131072, n = r >> 8, k = r & 255;
        fWT[idx] = __float2bfloat16(fW3[k * 128 + n]);
    } else if (idx < 180224) {
        int r = idx - 163840, n = r >> 7, k = r & 127;
        float v = (n < 64) ? fW4[k * 64 + n] : 0.f;
        fWT[idx] = __float2bfloat16(v);
    } else if (idx < 180352) {
        int i = idx - 180224;
        fb4p[i] = (i < 64) ? fb4[i] : 0.f;
    }
}

// ---------------- conv1 via MFMA + fused maxpool2 (XCD-swizzled flat grid)
__global__ __launch_bounds__(256) void conv1m_kernel(
        const bf16* __restrict__ img, const bf16* __restrict__ Wc1,
        const float* __restrict__ cb1, bf16* __restrict__ out) {
    int wid = xcd_swz(blockIdx.x, NIMG * 27);
    int n = wid / 27, chunk = wid % 27;
    int wv = threadIdx.x >> 6, ln = threadIdx.x & 63;
    int pr = ln & 15, kg = ln >> 4;
    int t0 = (chunk * 4 + wv) * 16;
    int t = t0 + pr;
    int tc = t < 1681 ? t : 1680;
    int pyt = tc / 41, pxt = tc % 41;
    const bf16* ib = img + (size_t)n * 28224;

    short8 wf[4][2];
    #pragma unroll
    for (int mt = 0; mt < 4; ++mt)
        #pragma unroll
        for (int h = 0; h < 2; ++h)
            wf[mt][h] = *(const short8*)&Wc1[(size_t)(mt * 16 + pr) * 64 + h * 32 + kg * 8];

    int r8 = (kg & 1) * 8;
    int kyb = kg >> 1;
    short8 pf[4][2];
    #pragma unroll
    for (int nt = 0; nt < 4; ++nt) {
        int py = 2 * pyt + (nt >> 1), px = 2 * pxt + (nt & 1);
        #pragma unroll
        for (int h = 0; h < 2; ++h) {
            int ky = h * 2 + kyb;
            short8 f = {0, 0, 0, 0, 0, 0, 0, 0};
            if (ky < 3) {
                const bf16* p = ib + ((py + ky) * 84 + px) * 4 + r8;
                if (r8 == 0) {
                    bfx4 a0 = *(const bfx4*)p, a1 = *(const bfx4*)(p + 4);
                    f[0] = a0[0]; f[1] = a0[1]; f[2] = a0[2]; f[3] = a0[3];
                    f[4] = a1[0]; f[5] = a1[1]; f[6] = a1[2]; f[7] = a1[3];
                } else {
                    bfx4 a0 = *(const bfx4*)p;
                    f[0] = a0[0]; f[1] = a0[1]; f[2] = a0[2]; f[3] = a0[3];
                }
            }
            pf[nt][h] = f;
        }
    }

    f32x4 acc[4][4];
    #pragma unroll
    for (int a = 0; a < 4; ++a)
        #pragma unroll
        for (int b = 0; b < 4; ++b)
            #pragma unroll
            for (int r = 0; r < 4; ++r) acc[a][b][r] = 0.f;

    #pragma unroll
    for (int h = 0; h < 2; ++h)
        #pragma unroll
        for (int mt = 0; mt < 4; ++mt)
            #pragma unroll
            for (int nt = 0; nt < 4; ++nt)
                acc[mt][nt] = __builtin_amdgcn_mfma_f32_16x16x32_bf16(
                    wf[mt][h], pf[nt][h], acc[mt][nt], 0, 0, 0);

    if (t < 1681) {
        bf16* ob = out + ((size_t)n * 1681 + t) * 64;
        #pragma unroll
        for (int mt = 0; mt < 4; ++mt) {
            f32x4 v = acc[mt][0];
            #pragma unroll
            for (int nt = 1; nt < 4; ++nt)
                #pragma unroll
                for (int r = 0; r < 4; ++r) v[r] = fmaxf(v[r], acc[mt][nt][r]);
            bfx4 o;
            #pragma unroll
            for (int r = 0; r < 4; ++r) o[r] = bfbits(v[r] + cb1[mt * 16 + kg * 4 + r]);
            *(bfx4*)&ob[mt * 16 + kg * 4] = o;
        }
    }
}

// ---------------- NHWC BN stats + fused finalize (last-block pattern)
__global__ void stats_nhwc_kernel(const bf16* buf, int HW, float* partial,
                                  const float* gam, const float* bet,
                                  float* scsh, int* counter) {
    __shared__ float l1[256][8], l2[256][8];
    __shared__ int isLast;
    int blk = blockIdx.x;
    bool qg = blk >= NBS;
    int b0 = qg ? blk - NBS : blk;
    int nb = qg ? NBQ : NBS;
    const bf16* base = buf + (qg ? (size_t)NSUP * HW * 64 : 0);
    long rows = (long)(qg ? NQRY : NSUP) * HW;
    int tid = threadIdx.x;
    int sub = tid & 7, rl = tid >> 3;
    float s1[8], s2[8];
    #pragma unroll
    for (int j = 0; j < 8; ++j) { s1[j] = 0.f; s2[j] = 0.f; }
    for (long r = (long)b0 * 32 + rl; r < rows; r += (long)nb * 32) {
        short8 v = *(const short8*)&base[r * 64 + sub * 8];
        #pragma unroll
        for (int j = 0; j < 8; ++j) { float f = b2f(v[j]); s1[j] += f; s2[j] += f * f; }
    }
    #pragma unroll
    for (int j = 0; j < 8; ++j) { l1[tid][j] = s1[j]; l2[tid][j] = s2[j]; }
    __syncthreads();
    if (tid < 64) {
        int su = tid >> 3, j = tid & 7;
        float a = 0.f, b = 0.f;
        for (int k = 0; k < 32; ++k) { a += l1[su + k * 8][j]; b += l2[su + k * 8][j]; }
        partial[blk * 128 + tid] = a;
        partial[blk * 128 + 64 + tid] = b;
    }
    __threadfence();
    __syncthreads();
    if (tid == 0) isLast = (atomicAdd(counter, 1) == (NBS + NBQ) - 1);
    __syncthreads();
    if (!isLast) return;

    // finalize: 256 threads, 2 partial-lanes per (g,c) output
    int out = tid >> 1, part = tid & 1;
    int g = out >> 6, c = out & 63;
    int fb0 = g ? NBS : 0, fnb = g ? NBQ : NBS;
    float f1 = 0.f, f2 = 0.f;
    for (int b = fb0 + part; b < fb0 + fnb; b += 2) {
        f1 += partial[b * 128 + c];
        f2 += partial[b * 128 + 64 + c];
    }
    l1[tid][0] = f1; l2[tid][0] = f2;
    __syncthreads();
    if (part == 0) {
        f1 += l1[tid + 1][0];
        f2 += l2[tid + 1][0];
        float cnt = (float)((g ? NQRY : NSUP)) * (float)HW;
        float mean = f1 / cnt;
        float var = f2 / cnt - mean * mean;
        float istd = rsqrtf(var + 1e-5f);
        float sc = gam[c] * istd;
        scsh[out] = sc;
        scsh[128 + out] = bet[c] - mean * sc;
    }
}

// ---------------- BN apply + relu in place
__global__ void bnrelu_nhwc_kernel(bf16* buf, const float* scsh, int HW, int total8) {
    int idx = blockIdx.x * 256 + threadIdx.x;
    if (idx >= total8) return;
    size_t e0 = (size_t)idx * 8;
    int c0 = (int)(e0 & 63);
    int g = (int)(e0 / ((size_t)HW * 64)) >= NSUP ? 1 : 0;
    short8 v = *(short8*)&buf[e0];
    short8 o;
    #pragma unroll
    for (int j = 0; j < 8; ++j) {
        int c = c0 + j;
        float f = b2f(v[j]) * scsh[g * 64 + c] + scsh[128 + g * 64 + c];
        o[j] = bfbits(fmaxf(f, 0.f));
    }
    *(short8*)&buf[e0] = o;
}

// ---------------- MFMA implicit-GEMM 3x3 conv with explicit 1-step pf prefetch
template <int IW, int OW, bool POOL, int NT>
__global__ __launch_bounds__(256) void convmfma_kernel(
        const bf16* __restrict__ in, const bf16* __restrict__ Wp,
        const float* __restrict__ cb, bf16* __restrict__ out, int nwg) {
    constexpr int M  = OW * OW;
    constexpr int PW = OW / 2;
    constexpr int MP = POOL ? PW * PW : M;
    constexpr int T  = NIMG * MP;
    constexpr int NPF = POOL ? 4 : NT;

    int wid = xcd_swz(blockIdx.x, nwg);
    int wv = threadIdx.x >> 6, ln = threadIdx.x & 63;
    int pr = ln & 15, kg = ln >> 4;

    const bf16* pptr[NPF];
    int pxv[NPF];
    if (POOL) {
        int gp = (wid * 4 + wv) * 16 + pr;
        int gpc = gp < T ? gp : T - 1;
        pxv[0] = gp;
        int n = gpc / MP, pp = gpc % MP;
        int py = pp / PW, px = pp % PW;
        const bf16* ib = in + (size_t)n * (IW * IW * 64) + kg * 8;
        #pragma unroll
        for (int nt = 0; nt < 4; ++nt)
            pptr[nt] = ib + ((2 * py + (nt >> 1)) * IW + 2 * px + (nt & 1)) * 64;
    } else {
        #pragma unroll
        for (int nt = 0; nt < NT; ++nt) {
            int gp = (wid * 4 + wv) * (16 * NT) + nt * 16 + pr;
            int gpc = gp < T ? gp : T - 1;
            pxv[nt] = gp;
            int n = gpc / M, pix = gpc % M;
            int y = pix / OW, x = pix % OW;
            pptr[nt] = in + ((size_t)n * (IW * IW) + y * IW + x) * 64 + kg * 8;
        }
    }
    const bf16* wb = Wp + kg * 8;

    f32x4 acc[4][NPF];
    #pragma unroll
    for (int a = 0; a < 4; ++a)
        #pragma unroll
        for (int b = 0; b < NPF; ++b)
            #pragma unroll
            for (int r = 0; r < 4; ++r) acc[a][b][r] = 0.f;

    short8 pf_c[NPF];
    #pragma unroll
    for (int nt = 0; nt < NPF; ++nt) pf_c[nt] = *(const short8*)(pptr[nt]);
    #pragma unroll
    for (int s = 0; s < 18; ++s) {
        short8 pf_n[NPF];
        if (s < 17) {
            int s2 = s + 1, tap2 = s2 >> 1, h2 = s2 & 1;
            int off2 = ((tap2 / 3) * IW + (tap2 % 3)) * 64 + h2 * 32;
            #pragma unroll
            for (int nt = 0; nt < NPF; ++nt)
                pf_n[nt] = *(const short8*)(pptr[nt] + off2);
        }
        int wk = s * 32;
        short8 wf[4];
        #pragma unroll
        for (int mt = 0; mt < 4; ++mt)
            wf[mt] = *(const short8*)(wb + (size_t)(mt * 16 + pr) * 584 + wk);
        #pragma unroll
        for (int mt = 0; mt < 4; ++mt)
            #pragma unroll
            for (int nt = 0; nt < NPF; ++nt)
                acc[mt][nt] = __builtin_amdgcn_mfma_f32_16x16x32_bf16(
                    wf[mt], pf_c[nt], acc[mt][nt], 0, 0, 0);
        if (s < 17) {
            #pragma unroll
            for (int nt = 0; nt < NPF; ++nt) pf_c[nt] = pf_n[nt];
        }
    }

    if (POOL) {
        int gp = pxv[0];
        if (gp < T) {
            bf16* ob = out + (size_t)gp * 64;
            #pragma unroll
            for (int mt = 0; mt < 4; ++mt) {
                f32x4 v = acc[mt][0];
                #pragma unroll
                for (int nt = 1; nt < 4; ++nt)
                    #pragma unroll
                    for (int r = 0; r < 4; ++r) v[r] = fmaxf(v[r], acc[mt][nt][r]);
                bfx4 o;
                #pragma unroll
                for (int r = 0; r < 4; ++r) o[r] = bfbits(v[r] + cb[mt * 16 + kg * 4 + r]);
                *(bfx4*)&ob[mt * 16 + kg * 4] = o;
            }
        }
    } else {
        #pragma unroll
        for (int mt = 0; mt < 4; ++mt) {
            float bv[4];
            #pragma unroll
            for (int r = 0; r < 4; ++r) bv[r] = cb[mt * 16 + kg * 4 + r];
            #pragma unroll
            for (int nt = 0; nt < NPF; ++nt) {
                if (pxv[nt] < T) {
                    bfx4 o;
                    #pragma unroll
                    for (int r = 0; r < 4; ++r) o[r] = bfbits(acc[mt][nt][r] + bv[r]);
                    *(bfx4*)&out[(size_t)pxv[nt] * 64 + mt * 16 + kg * 4] = o;
                }
            }
        }
    }
}

// ---------------- fused BN4+relu+avgpool5 + projection (block = image)
__global__ void bnpool_proj_kernel(const bf16* buf4, const float* scsh,
                                   const float* gW1, float* A, float* Bq) {
    __shared__ float fs[576];
    int n = blockIdx.x;
    int g = n >= NSUP;
    int tid = threadIdx.x;
    for (int e = tid; e < 576; e += 256) {
        int c = e / 9, p9 = e % 9;
        float sc = scsh[g * 64 + c], sh = scsh[128 + g * 64 + c];
        int ii = p9 / 3, jj = p9 % 3;
        const bf16* base = buf4 + ((size_t)n * 225 + ii * 5 * 15 + jj * 5) * 64 + c;
        float s = 0;
        #pragma unroll
        for (int u = 0; u < 5; ++u)
            #pragma unroll
            for (int v = 0; v < 5; ++v)
                s += fmaxf(__bfloat162float(base[(u * 15 + v) * 64]) * sc + sh, 0.f);
        fs[e] = s * 0.04f;
    }
    __syncthreads();
    int k = tid;
    const float* W = g ? gW1 + 66 * 256 : gW1;
    float* out = g ? Bq + (size_t)(n - NSUP) * 9 * 256 : A + (size_t)n * 9 * 256;
    for (int p = 0; p < 9; ++p) {
        float acc = 0;
        for (int c = 0; c < 64; ++c) acc += fs[c * 9 + p] * W[c * 256 + k];
        acc += ((float)(p / 3) * (1.f / 3.f)) * W[64 * 256 + k];
        acc += ((float)(p % 3) * (1.f / 3.f)) * W[65 * 256 + k];
        out[p * 256 + k] = acc;
    }
}

// ---------------- H0 = relu(A + Bq + gb1), bf16, [GMP][256]
__global__ void h0_kernel(const float* A, const float* Bq, const float* gb1, bf16* H) {
    int tid = threadIdx.x;
    int row = blockIdx.x * 8 + (tid >> 5);
    int col = (tid & 31) * 8;
    short8 o;
    if (row < GM) {
        int bqs = row / 81, r81 = row % 81;
        int ps = r81 / 9, pq = r81 % 9;
        int b = bqs / 75, r75 = bqs % 75, q = r75 / 5, s = r75 % 5;
        const float* Ar = A + ((size_t)((b * 5 + s) * 9 + ps)) * 256 + col;
        const float* Br = Bq + ((size_t)((b * 15 + q) * 9 + pq)) * 256 + col;
        #pragma unroll
        for (int j = 0; j < 8; ++j) {
            float v = Ar[j] + Br[j] + gb1[col + j];
            o[j] = bfbits(fmaxf(v, 0.f));
        }
    } else {
        #pragma unroll
        for (int j = 0; j < 8; ++j) o[j] = 0;
    }
    *(short8*)&H[(size_t)row * 256 + col] = o;
}

// ---------------- generalized MFMA GEMM (double-buffered global_load_lds)
template <int KT, bool RELU, bool F32OUT>
__global__ __launch_bounds__(256) void gemm_f_kernel(
        const bf16* __restrict__ Ain, const bf16* __restrict__ WT,
        const float* __restrict__ bias, void* __restrict__ outv, int ldo) {
    constexpr int K = KT * 32;
    __shared__ __align__(16) short As[2][4096];
    __shared__ __align__(16) short Bs[2][4096];
    int bm0 = blockIdx.x * 128;
    int bn0 = blockIdx.y * 128;
    int tid = threadIdx.x, wv = tid >> 6, ln = tid & 63;
    int wm = wv >> 1, wn = wv & 1;

    int srow = (wv * 2) * 16 + (ln >> 2);
    int scol = (ln & 3) * 8;
    const bf16* Ag = Ain + (size_t)(bm0 + srow) * K + scol;
    const bf16* Bg = WT + (size_t)(bn0 + srow) * K + scol;

    f32x4 acc[4][4];
    #pragma unroll
    for (int m = 0; m < 4; ++m)
        #pragma unroll
        for (int n = 0; n < 4; ++n)
            #pragma unroll
            for (int r = 0; r < 4; ++r) acc[m][n][r] = 0.f;

    int ar = (wm * 64 + (ln & 15)) * 32 + (ln >> 4) * 8;
    int br = (wn * 64 + (ln & 15)) * 32 + (ln >> 4) * 8;

    GLL(Ag,          &As[0][(wv * 2) * 512]);
    GLL(Ag + 16 * K, &As[0][(wv * 2 + 1) * 512]);
    GLL(Bg,          &Bs[0][(wv * 2) * 512]);
    GLL(Bg + 16 * K, &Bs[0][(wv * 2 + 1) * 512]);
    __syncthreads();

    int cur = 0;
    for (int kt = 0; kt < KT; ++kt) {
        if (kt < KT - 1) {
            int k0 = (kt + 1) * 32;
            GLL(Ag + k0,          &As[cur ^ 1][(wv * 2) * 512]);
            GLL(Ag + 16 * K + k0, &As[cur ^ 1][(wv * 2 + 1) * 512]);
            GLL(Bg + k0,          &Bs[cur ^ 1][(wv * 2) * 512]);
            GLL(Bg + 16 * K + k0, &Bs[cur ^ 1][(wv * 2 + 1) * 512]);
        }
        short8 a[4], b[4];
        #pragma unroll
        for (int m = 0; m < 4; ++m) a[m] = *(const short8*)&As[cur][ar + m * 512];
        #pragma unroll
        for (int n = 0; n < 4; ++n) b[n] = *(const short8*)&Bs[cur][br + n * 512];
        #pragma unroll
        for (int m = 0; m < 4; ++m)
            #pragma unroll
            for (int n = 0; n < 4; ++n)
                acc[m][n] = __builtin_amdgcn_mfma_f32_16x16x32_bf16(a[m], b[n], acc[m][n], 0, 0, 0);
        __syncthreads();
        cur ^= 1;
    }

    int orow = bm0 + wm * 64 + (ln >> 4) * 4;
    int ocol = bn0 + wn * 64 + (ln & 15);
    #pragma unroll
    for (int n = 0; n < 4; ++n) {
        float bv = bias[ocol + n * 16];
        #pragma unroll
        for (int m = 0; m < 4; ++m) {
            #pragma unroll
            for (int r = 0; r < 4; ++r) {
                float v = acc[m][n][r] + bv;
                if (RELU) v = fmaxf(v, 0.f);
                size_t oi = (size_t)(orow + m * 16 + r) * ldo + ocol + n * 16;
                if (F32OUT) ((float*)outv)[oi] = v;
                else        ((bf16*)outv)[oi] = __float2bfloat16(v);
            }
        }
    }
}

// ---------------- xf (bf16, padded to 640 rows) = sum over 81 rows of H3, vectorized
__global__ void xfred_kernel(const bf16* H, bf16* xfb) {
    int bqs = blockIdx.x, tid = threadIdx.x;
    int sub = tid & 31, rl = tid >> 5;
    float s[8];
    #pragma unroll
    for (int j = 0; j < 8; ++j) s[j] = 0.f;
    if (bqs < 600) {
        const bf16* p = H + (size_t)bqs * 81 * 256 + sub * 8;
        for (int r = rl; r < 81; r += 8) {
            short8 v = *(const short8*)&p[r * 256];
            #pragma unroll
            for (int j = 0; j < 8; ++j) s[j] += b2f(v[j]);
        }
    }
    __shared__ float red[256][8];
    #pragma unroll
    for (int j = 0; j < 8; ++j) red[tid][j] = s[j];
    __syncthreads();
    if (tid < 32) {
        short8 o;
        #pragma unroll
        for (int j = 0; j < 8; ++j) {
            float t = 0;
            #pragma unroll
            for (int k = 0; k < 8; ++k) t += red[k * 32 + tid][j];
            o[j] = bfbits(t);
        }
        *(short8*)&xfb[(size_t)bqs * 256 + tid * 8] = o;
    }
}

// ---------------- score + fused final loss reduce (last-block pattern)
__global__ void score_kernel(const float* F4, const int* sy, const int* qy,
                             float* lossp, float* outp, int* counter) {
    __shared__ float scs[8];
    __shared__ int isLast;
    __shared__ float r[128];
    int bid = blockIdx.x;
    int tid = threadIdx.x;
    int s = tid >> 6, k = tid & 63;
    float v = F4[(size_t)(bid * 5 + s) * 128 + k];
    float sum = v * v;
    #pragma unroll
    for (int m = 1; m < 64; m <<= 1) sum += __shfl_xor(sum, m);
    if (k == 0) scs[s] = sqrtf(sum);
    __syncthreads();
    if (tid == 0) {
        int b = bid / 15, q = bid % 15;
        float n2 = 0;
        for (int j = 0; j < 5; ++j) n2 += scs[j] * scs[j];
        float n = sqrtf(n2);
        float f = n / (1.f + n2);
        int qyv = qy[b * 15 + q];
        float sc[5]; bool ap[5]; float sap = 0;
        for (int j = 0; j < 5; ++j) {
            sc[j] = scs[j] * f;
            ap[j] = (sy[b * 5 + j] == qyv);
            if (ap[j]) sap += sc[j];
        }
        float lp = 0;
        for (int j = 0; j < 5; ++j)
            if (!ap[j]) lp += fmaxf(sc[j] - sap + 0.2f, 0.f);
        lossp[bid] = lp;
    }
    __threadfence();
    __syncthreads();
    if (tid == 0) isLast = (atomicAdd(counter, 1) == gridDim.x - 1);
    __syncthreads();
    if (!isLast) return;
    if (tid < 128) r[tid] = (tid < NQRY) ? lossp[tid] : 0.f;
    __syncthreads();
    for (int off2 = 64; off2; off2 >>= 1) {
        if (tid < off2) r[tid] += r[tid + off2];
        __syncthreads();
    }
    if (tid == 0) outp[0] = r[0];
}

extern "C" void kernel_launch(void* const* d_in, const int* in_sizes, int n_in,
                              void* d_out, int out_size, void* d_ws, size_t ws_size,
                              hipStream_t stream) {
    const float* sx  = (const float*)d_in[0];
    const int*   syp = (const int*)d_in[1];
    const float* qx  = (const float*)d_in[2];
    const int*   qyp = (const int*)d_in[3];
    const float* cw1 = (const float*)d_in[4];  const float* cb1 = (const float*)d_in[5];
    const float* bg1 = (const float*)d_in[6];  const float* bb1 = (const float*)d_in[7];
    const float* cw2 = (const float*)d_in[8];  const float* cb2 = (const float*)d_in[9];
    const float* bg2 = (const float*)d_in[10]; const float* bb2 = (const float*)d_in[11];
    const float* cw3 = (const float*)d_in[12]; const float* cb3 = (const float*)d_in[13];
    const float* bg3 = (const float*)d_in[14]; const float* bb3 = (const float*)d_in[15];
    const float* cw4 = (const float*)d_in[16]; const float* cb4 = (const float*)d_in[17];
    const float* bg4 = (const float*)d_in[18]; const float* bb4 = (const float*)d_in[19];
    const float* gW1 = (const float*)d_in[20]; const float* gb1 = (const float*)d_in[21];
    const float* gW2 = (const float*)d_in[22]; const float* gb2 = (const float*)d_in[23];
    const float* gW3 = (const float*)d_in[24]; const float* gb3 = (const float*)d_in[25];
    const float* gW4 = (const float*)d_in[26]; const float* gb4 = (const float*)d_in[27];
    const float* fW1 = (const float*)d_in[28]; const float* fb1 = (const float*)d_in[29];
    const float* fW2 = (const float*)d_in[30]; const float* fb2 = (const float*)d_in[31];
    const float* fW3 = (const float*)d_in[32]; const float* fb3 = (const float*)d_in[33];
    const float* fW4 = (const float*)d_in[34]; const float* fb4 = (const float*)d_in[35];

    char* w = (char*)d_ws;
    size_t off = 0;
    bf16*  buf1  = (bf16*)(w + off); off += 34426880ull;  // [160][1681][64] bf16
    bf16*  hbuf  = (bf16*)(w + off); off += 31150080ull;  // H ping-pong region B
    bf16*  pbuf2 = (bf16*)(w + off); off += 7393280ull;   // [160][361][64] bf16
    bf16*  buf3  = (bf16*)(w + off); off += 5918720ull;   // [160][289][64] bf16
    bf16*  buf4  = (bf16*)(w + off); off += 4608000ull;   // [160][225][64] bf16
    float* Abuf  = (float*)(w + off); off += 368640ull;   // 40x9x256
    float* Bbuf  = (float*)(w + off); off += 1105920ull;  // 120x9x256
    bf16*  xfb   = (bf16*)(w + off); off += 327680ull;    // [640][256] bf16
    bf16*  F1    = (bf16*)(w + off); off += 327680ull;    // [640][256] bf16
    bf16*  F2    = (bf16*)(w + off); off += 327680ull;    // [640][256] bf16
    bf16*  F3    = (bf16*)(w + off); off += 163840ull;    // [640][128] bf16
    float* F4    = (float*)(w + off); off += 327680ull;   // [640][128] f32
    float* partial = (float*)(w + off); off += 262144ull; // 512 x 128 f32
    float* scsh  = (float*)(w + off); off += 4096ull;     // 4 stages x 256
    bf16*  imgN  = (bf16*)(w + off); off += 9031680ull;   // [160][84][84][4] bf16
    bf16*  Wc1   = (bf16*)(w + off); off += 8192ull;      // [64][64] bf16
    bf16*  Wp    = (bf16*)(w + off); off += 224256ull;    // 3 x 64 x 584 bf16
    bf16*  WTg   = (bf16*)(w + off); off += 393216ull;    // 3 x 256x256 bf16
    bf16*  fWT   = (bf16*)(w + off); off += 360448ull;    // f-chain weights bf16 [n][k]
    float* fb4p  = (float*)(w + off); off += 512ull;      // padded fb4 [128]
    float* lossp = (float*)(w + off); off += 512ull;
    int*   counters = (int*)(w + off); off += 64ull;      // 8 atomic counters

    float* scsh1 = scsh;        float* scsh2 = scsh + 256;
    float* scsh3 = scsh + 512;  float* scsh4 = scsh + 768;
    bf16* Wp2 = Wp;
    bf16* Wp3 = Wp + 64 * 584;
    bf16* Wp4 = Wp + 2 * 64 * 584;
    bf16* fWT1 = fWT;
    bf16* fWT2 = fWT + 65536;
    bf16* fWT3 = fWT + 131072;
    bf16* fWT4 = fWT + 163840;

    // H ping-pong reuses dead conv buffers
    bf16* Hb0 = buf1;            // 24.9 MB <= 34.4 MB
    bf16* Hb1 = hbuf;            // 24.9 MB <= 31.2 MB

    // fused prep: nhwc4 (1128960 elems) + weight prep (493184) + counter zero
    prep_kernel<<<(1128960 + 493184 + 255) / 256, 256, 0, stream>>>(
        sx, qx, imgN, cw1, cw2, cw3, cw4, gW2, gW3, gW4,
        fW1, fW2, fW3, fW4, fb4, Wc1, Wp, WTg, fWT, fb4p, counters);

    // stage 1
    conv1m_kernel<<<NIMG * 27, 256, 0, stream>>>(imgN, Wc1, cb1, buf1);
    stats_nhwc_kernel<<<NBS + NBQ, 256, 0, stream>>>(buf1, 1681, partial, bg1, bb1, scsh1, counters + 0);
    bnrelu_nhwc_kernel<<<(2151680 + 255) / 256, 256, 0, stream>>>(buf1, scsh1, 1681, 2151680);

    // stage 2
    convmfma_kernel<41, 39, true, 4><<<dim3(903), 256, 0, stream>>>(buf1, Wp2, cb2, pbuf2, 903);
    stats_nhwc_kernel<<<NBS + NBQ, 256, 0, stream>>>(pbuf2, 361, partial, bg2, bb2, scsh2, counters + 1);
    bnrelu_nhwc_kernel<<<(462080 + 255) / 256, 256, 0, stream>>>(pbuf2, scsh2, 361, 462080);

    // stage 3
    convmfma_kernel<19, 17, false, 2><<<dim3(362), 256, 0, stream>>>(pbuf2, Wp3, cb3, buf3, 362);
    stats_nhwc_kernel<<<NBS + NBQ, 256, 0, stream>>>(buf3, 289, partial, bg3, bb3, scsh3, counters + 2);
    bnrelu_nhwc_kernel<<<(369920 + 255) / 256, 256, 0, stream>>>(buf3, scsh3, 289, 369920);

    // stage 4
    convmfma_kernel<17, 15, false, 2><<<dim3(282), 256, 0, stream>>>(buf3, Wp4, cb4, buf4, 282);
    stats_nhwc_kernel<<<NBS + NBQ, 256, 0, stream>>>(buf4, 225, partial, bg4, bb4, scsh4, counters + 3);
    bnpool_proj_kernel<<<NIMG, 256, 0, stream>>>(buf4, scsh4, gW1, Abuf, Bbuf);

    // g-MLP as split MFMA GEMM chain
    h0_kernel<<<GMP / 8, 256, 0, stream>>>(Abuf, Bbuf, gb1, Hb0);
    dim3 ggrid(GMP / 128, 2);
    gemm_f_kernel<8, true, false><<<ggrid, 256, 0, stream>>>(Hb0, WTg,          gb2, (void*)Hb1, 256);
    gemm_f_kernel<8, true, false><<<ggrid, 256, 0, stream>>>(Hb1, WTg + 65536,  gb3, (void*)Hb0, 256);
    gemm_f_kernel<8, true, false><<<ggrid, 256, 0, stream>>>(Hb0, WTg + 131072, gb4, (void*)Hb1, 256);
    xfred_kernel<<<640, 256, 0, stream>>>(Hb1, xfb);

    // f-chain as batched MFMA GEMMs
    gemm_f_kernel<8, true,  false><<<dim3(5, 2), 256, 0, stream>>>(xfb, fWT1, fb1,  (void*)F1, 256);
    gemm_f_kernel<8, true,  false><<<dim3(5, 2), 256, 0, stream>>>(F1,  fWT2, fb2,  (void*)F2, 256);
    gemm_f_kernel<8, true,  false><<<dim3(5, 1), 256, 0, stream>>>(F2,  fWT3, fb3,  (void*)F3, 128);
    gemm_f_kernel<4, false, true ><<<dim3(5, 1), 256, 0, stream>>>(F3,  fWT4, fb4p, (void*)F4, 128);

    // score + fused final reduce
    score_kernel<<<NQRY, 320, 0, stream>>>(F4, syp, qyp, lossp, (float*)d_out, counters + 4);
}

// Round 16
// 383.758 us; speedup vs baseline: 1.6895x; 1.6895x over previous
//
#include <hip/hip_runtime.h>
#include <hip/hip_bf16.h>

typedef __hip_bfloat16 bf16;
typedef __attribute__((ext_vector_type(8))) short short8;
typedef __attribute__((ext_vector_type(4))) short bfx4;
typedef __attribute__((ext_vector_type(4))) float f32x4;

#define DEV __device__ __forceinline__

static constexpr int NSUP = 40;    // B*N_WAY*K_SHOT
static constexpr int NQRY = 120;   // B*Q
static constexpr int NIMG = 160;
static constexpr int GM   = 48600; // 600 * 81 rows of the g-MLP
static constexpr int GMP  = 48640; // padded to 380*128
static constexpr int NBS  = 128;   // stats blocks for support group
static constexpr int NBQ  = 384;   // stats blocks for query group

DEV float b2f(short s) {
    union { unsigned int u; float f; } v; v.u = ((unsigned int)(unsigned short)s) << 16; return v.f;
}
DEV short bfbits(float v) {
    bf16 h = __float2bfloat16(v);
    union { bf16 b; short s; } u; u.b = h; return u.s;
}

// bijective XCD swizzle (m204)
DEV int xcd_swz(int b, int nwg) {
    int q = nwg >> 3, r = nwg & 7;
    int x = b & 7, i = b >> 3;
    return (x < r) ? x * (q + 1) + i : r * (q + 1) + (x - r) * q + i;
}

#define GLL(gp, lp) __builtin_amdgcn_global_load_lds( \
    (const __attribute__((address_space(1))) void*)(gp), \
    (__attribute__((address_space(3))) void*)(lp), 16, 0, 0)

// ---------------- fused prep: input->NHWC4 + all weight transforms (no atomics)
__global__ void prep_kernel(const float* sx, const float* qx, bf16* img,
                            const float* cw1, const float* cw2, const float* cw3,
                            const float* cw4, const float* gW2, const float* gW3,
                            const float* gW4, const float* fW1, const float* fW2,
                            const float* fW3, const float* fW4, const float* fb4,
                            bf16* Wc1, bf16* Wp, bf16* WTg, bf16* fWT, float* fb4p) {
    long gid = (long)blockIdx.x * 256 + threadIdx.x;
    if (gid < (long)NIMG * 7056) {
        int n = (int)(gid / 7056), p = (int)(gid % 7056);
        const float* im = ((n < NSUP) ? sx + (size_t)n * 3 * 7056
                                      : qx + (size_t)(n - NSUP) * 3 * 7056) + p;
        bfx4 o;
        o[0] = bfbits(im[0]);
        o[1] = bfbits(im[7056]);
        o[2] = bfbits(im[14112]);
        o[3] = 0;
        *(bfx4*)&img[gid * 4] = o;
        return;
    }
    int idx = (int)(gid - (long)NIMG * 7056);
    if (idx < 4096) {
        int oc = idx >> 6, k = idx & 63;
        int ky = k >> 4, r = k & 15;
        float v = 0.f;
        if (ky < 3 && r < 12) {
            int kx = r >> 2, ic = r & 3;
            if (ic < 3) v = cw1[oc * 27 + ic * 9 + ky * 3 + kx];
        }
        Wc1[idx] = __float2bfloat16(v);
        return;
    }
    idx -= 4096;
    if (idx < 3 * 64 * 584) {
        int L = idx / (64 * 584), r = idx % (64 * 584);
        int oc = r / 584, kk = r % 584;
        const float* src = (L == 0) ? cw2 : (L == 1) ? cw3 : cw4;
        float v = 0.f;
        if (kk < 576) {
            int ic = kk & 63, tap = kk >> 6;
            v = src[oc * 576 + ic * 9 + tap];
        }
        Wp[idx] = __float2bfloat16(v);
        return;
    }
    idx -= 3 * 64 * 584;
    if (idx < 3 * 65536) {
        int L = idx >> 16, r = idx & 65535, n = r >> 8, k = r & 255;
        const float* W = (L == 0) ? gW2 : (L == 1) ? gW3 : gW4;
        WTg[idx] = __float2bfloat16(W[k * 256 + n]);
        return;
    }
    idx -= 3 * 65536;
    if (idx < 65536) {
        int n = idx >> 8, k = idx & 255;
        fWT[idx] = __float2bfloat16(fW1[k * 256 + n]);
    } else if (idx < 131072) {
        int r = idx - 65536, n = r >> 8, k = r & 255;
        fWT[idx] = __float2bfloat16(fW2[k * 256 + n]);
    } else if (idx < 163840) {
        int r = idx - 131072, n = r >> 8, k = r & 255;
        fWT[idx] = __float2bfloat16(fW3[k * 128 + n]);
    } else if (idx < 180224) {
        int r = idx - 163840, n = r >> 7, k = r & 127;
        float v = (n < 64) ? fW4[k * 64 + n] : 0.f;
        fWT[idx] = __float2bfloat16(v);
    } else if (idx < 180352) {
        int i = idx - 180224;
        fb4p[i] = (i < 64) ? fb4[i] : 0.f;
    }
}

// ---------------- conv1 via MFMA + fused maxpool2 (XCD-swizzled flat grid)
__global__ __launch_bounds__(256) void conv1m_kernel(
        const bf16* __restrict__ img, const bf16* __restrict__ Wc1,
        const float* __restrict__ cb1, bf16* __restrict__ out) {
    int wid = xcd_swz(blockIdx.x, NIMG * 27);
    int n = wid / 27, chunk = wid % 27;
    int wv = threadIdx.x >> 6, ln = threadIdx.x & 63;
    int pr = ln & 15, kg = ln >> 4;
    int t0 = (chunk * 4 + wv) * 16;
    int t = t0 + pr;
    int tc = t < 1681 ? t : 1680;
    int pyt = tc / 41, pxt = tc % 41;
    const bf16* ib = img + (size_t)n * 28224;

    short8 wf[4][2];
    #pragma unroll
    for (int mt = 0; mt < 4; ++mt)
        #pragma unroll
        for (int h = 0; h < 2; ++h)
            wf[mt][h] = *(const short8*)&Wc1[(size_t)(mt * 16 + pr) * 64 + h * 32 + kg * 8];

    int r8 = (kg & 1) * 8;
    int kyb = kg >> 1;
    short8 pf[4][2];
    #pragma unroll
    for (int nt = 0; nt < 4; ++nt) {
        int py = 2 * pyt + (nt >> 1), px = 2 * pxt + (nt & 1);
        #pragma unroll
        for (int h = 0; h < 2; ++h) {
            int ky = h * 2 + kyb;
            short8 f = {0, 0, 0, 0, 0, 0, 0, 0};
            if (ky < 3) {
                const bf16* p = ib + ((py + ky) * 84 + px) * 4 + r8;
                if (r8 == 0) {
                    bfx4 a0 = *(const bfx4*)p, a1 = *(const bfx4*)(p + 4);
                    f[0] = a0[0]; f[1] = a0[1]; f[2] = a0[2]; f[3] = a0[3];
                    f[4] = a1[0]; f[5] = a1[1]; f[6] = a1[2]; f[7] = a1[3];
                } else {
                    bfx4 a0 = *(const bfx4*)p;
                    f[0] = a0[0]; f[1] = a0[1]; f[2] = a0[2]; f[3] = a0[3];
                }
            }
            pf[nt][h] = f;
        }
    }

    f32x4 acc[4][4];
    #pragma unroll
    for (int a = 0; a < 4; ++a)
        #pragma unroll
        for (int b = 0; b < 4; ++b)
            #pragma unroll
            for (int r = 0; r < 4; ++r) acc[a][b][r] = 0.f;

    #pragma unroll
    for (int h = 0; h < 2; ++h)
        #pragma unroll
        for (int mt = 0; mt < 4; ++mt)
            #pragma unroll
            for (int nt = 0; nt < 4; ++nt)
                acc[mt][nt] = __builtin_amdgcn_mfma_f32_16x16x32_bf16(
                    wf[mt][h], pf[nt][h], acc[mt][nt], 0, 0, 0);

    if (t < 1681) {
        bf16* ob = out + ((size_t)n * 1681 + t) * 64;
        #pragma unroll
        for (int mt = 0; mt < 4; ++mt) {
            f32x4 v = acc[mt][0];
            #pragma unroll
            for (int nt = 1; nt < 4; ++nt)
                #pragma unroll
                for (int r = 0; r < 4; ++r) v[r] = fmaxf(v[r], acc[mt][nt][r]);
            bfx4 o;
            #pragma unroll
            for (int r = 0; r < 4; ++r) o[r] = bfbits(v[r] + cb1[mt * 16 + kg * 4 + r]);
            *(bfx4*)&ob[mt * 16 + kg * 4] = o;
        }
    }
}

// ---------------- NHWC BN stats, vectorized short8 (no fence, no atomics)
__global__ void stats_nhwc_kernel(const bf16* buf, int HW, float* partial) {
    int blk = blockIdx.x;
    bool qg = blk >= NBS;
    int b0 = qg ? blk - NBS : blk;
    int nb = qg ? NBQ : NBS;
    const bf16* base = buf + (qg ? (size_t)NSUP * HW * 64 : 0);
    long rows = (long)(qg ? NQRY : NSUP) * HW;
    int tid = threadIdx.x;
    int sub = tid & 7, rl = tid >> 3;
    float s1[8], s2[8];
    #pragma unroll
    for (int j = 0; j < 8; ++j) { s1[j] = 0.f; s2[j] = 0.f; }
    for (long r = (long)b0 * 32 + rl; r < rows; r += (long)nb * 32) {
        short8 v = *(const short8*)&base[r * 64 + sub * 8];
        #pragma unroll
        for (int j = 0; j < 8; ++j) { float f = b2f(v[j]); s1[j] += f; s2[j] += f * f; }
    }
    __shared__ float l1[256][8], l2[256][8];
    #pragma unroll
    for (int j = 0; j < 8; ++j) { l1[tid][j] = s1[j]; l2[tid][j] = s2[j]; }
    __syncthreads();
    if (tid < 64) {
        int su = tid >> 3, j = tid & 7;
        float a = 0.f, b = 0.f;
        for (int k = 0; k < 32; ++k) { a += l1[su + k * 8][j]; b += l2[su + k * 8][j]; }
        partial[blk * 128 + tid] = a;
        partial[blk * 128 + 64 + tid] = b;
    }
}

// ---------------- finalize (parallel, separate launch)
__global__ __launch_bounds__(1024) void bnfin_kernel(
        const float* partial, const float* gam, const float* bet,
        int HW, float* scsh) {
    int tid = threadIdx.x;
    int out = tid >> 3;
    int part = tid & 7;
    int g = out >> 6, c = out & 63;
    int b0 = g ? NBS : 0, nb = g ? NBQ : NBS;
    float s1 = 0.f, s2 = 0.f;
    for (int b = b0 + part; b < b0 + nb; b += 8) {
        s1 += partial[b * 128 + c];
        s2 += partial[b * 128 + 64 + c];
    }
    __shared__ float r1[1024], r2[1024];
    r1[tid] = s1; r2[tid] = s2;
    __syncthreads();
    if (part == 0) {
        #pragma unroll
        for (int j = 1; j < 8; ++j) { s1 += r1[tid + j]; s2 += r2[tid + j]; }
        float cnt = (float)((g ? NQRY : NSUP)) * (float)HW;
        float mean = s1 / cnt;
        float var = s2 / cnt - mean * mean;
        float istd = rsqrtf(var + 1e-5f);
        float sc = gam[c] * istd;
        scsh[out] = sc;
        scsh[128 + out] = bet[c] - mean * sc;
    }
}

// ---------------- BN apply + relu in place
__global__ void bnrelu_nhwc_kernel(bf16* buf, const float* scsh, int HW, int total8) {
    int idx = blockIdx.x * 256 + threadIdx.x;
    if (idx >= total8) return;
    size_t e0 = (size_t)idx * 8;
    int c0 = (int)(e0 & 63);
    int g = (int)(e0 / ((size_t)HW * 64)) >= NSUP ? 1 : 0;
    short8 v = *(short8*)&buf[e0];
    short8 o;
    #pragma unroll
    for (int j = 0; j < 8; ++j) {
        int c = c0 + j;
        float f = b2f(v[j]) * scsh[g * 64 + c] + scsh[128 + g * 64 + c];
        o[j] = bfbits(fmaxf(f, 0.f));
    }
    *(short8*)&buf[e0] = o;
}

// ---------------- MFMA implicit-GEMM 3x3 conv with explicit 1-step pf prefetch
template <int IW, int OW, bool POOL, int NT>
__global__ __launch_bounds__(256) void convmfma_kernel(
        const bf16* __restrict__ in, const bf16* __restrict__ Wp,
        const float* __restrict__ cb, bf16* __restrict__ out, int nwg) {
    constexpr int M  = OW * OW;
    constexpr int PW = OW / 2;
    constexpr int MP = POOL ? PW * PW : M;
    constexpr int T  = NIMG * MP;
    constexpr int NPF = POOL ? 4 : NT;

    int wid = xcd_swz(blockIdx.x, nwg);
    int wv = threadIdx.x >> 6, ln = threadIdx.x & 63;
    int pr = ln & 15, kg = ln >> 4;

    const bf16* pptr[NPF];
    int pxv[NPF];
    if (POOL) {
        int gp = (wid * 4 + wv) * 16 + pr;
        int gpc = gp < T ? gp : T - 1;
        pxv[0] = gp;
        int n = gpc / MP, pp = gpc % MP;
        int py = pp / PW, px = pp % PW;
        const bf16* ib = in + (size_t)n * (IW * IW * 64) + kg * 8;
        #pragma unroll
        for (int nt = 0; nt < 4; ++nt)
            pptr[nt] = ib + ((2 * py + (nt >> 1)) * IW + 2 * px + (nt & 1)) * 64;
    } else {
        #pragma unroll
        for (int nt = 0; nt < NT; ++nt) {
            int gp = (wid * 4 + wv) * (16 * NT) + nt * 16 + pr;
            int gpc = gp < T ? gp : T - 1;
            pxv[nt] = gp;
            int n = gpc / M, pix = gpc % M;
            int y = pix / OW, x = pix % OW;
            pptr[nt] = in + ((size_t)n * (IW * IW) + y * IW + x) * 64 + kg * 8;
        }
    }
    const bf16* wb = Wp + kg * 8;

    f32x4 acc[4][NPF];
    #pragma unroll
    for (int a = 0; a < 4; ++a)
        #pragma unroll
        for (int b = 0; b < NPF; ++b)
            #pragma unroll
            for (int r = 0; r < 4; ++r) acc[a][b][r] = 0.f;

    short8 pf_c[NPF];
    #pragma unroll
    for (int nt = 0; nt < NPF; ++nt) pf_c[nt] = *(const short8*)(pptr[nt]);
    #pragma unroll
    for (int s = 0; s < 18; ++s) {
        short8 pf_n[NPF];
        if (s < 17) {
            int s2 = s + 1, tap2 = s2 >> 1, h2 = s2 & 1;
            int off2 = ((tap2 / 3) * IW + (tap2 % 3)) * 64 + h2 * 32;
            #pragma unroll
            for (int nt = 0; nt < NPF; ++nt)
                pf_n[nt] = *(const short8*)(pptr[nt] + off2);
        }
        int wk = s * 32;
        short8 wf[4];
        #pragma unroll
        for (int mt = 0; mt < 4; ++mt)
            wf[mt] = *(const short8*)(wb + (size_t)(mt * 16 + pr) * 584 + wk);
        #pragma unroll
        for (int mt = 0; mt < 4; ++mt)
            #pragma unroll
            for (int nt = 0; nt < NPF; ++nt)
                acc[mt][nt] = __builtin_amdgcn_mfma_f32_16x16x32_bf16(
                    wf[mt], pf_c[nt], acc[mt][nt], 0, 0, 0);
        if (s < 17) {
            #pragma unroll
            for (int nt = 0; nt < NPF; ++nt) pf_c[nt] = pf_n[nt];
        }
    }

    if (POOL) {
        int gp = pxv[0];
        if (gp < T) {
            bf16* ob = out + (size_t)gp * 64;
            #pragma unroll
            for (int mt = 0; mt < 4; ++mt) {
                f32x4 v = acc[mt][0];
                #pragma unroll
                for (int nt = 1; nt < 4; ++nt)
                    #pragma unroll
                    for (int r = 0; r < 4; ++r) v[r] = fmaxf(v[r], acc[mt][nt][r]);
                bfx4 o;
                #pragma unroll
                for (int r = 0; r < 4; ++r) o[r] = bfbits(v[r] + cb[mt * 16 + kg * 4 + r]);
                *(bfx4*)&ob[mt * 16 + kg * 4] = o;
            }
        }
    } else {
        #pragma unroll
        for (int mt = 0; mt < 4; ++mt) {
            float bv[4];
            #pragma unroll
            for (int r = 0; r < 4; ++r) bv[r] = cb[mt * 16 + kg * 4 + r];
            #pragma unroll
            for (int nt = 0; nt < NPF; ++nt) {
                if (pxv[nt] < T) {
                    bfx4 o;
                    #pragma unroll
                    for (int r = 0; r < 4; ++r) o[r] = bfbits(acc[mt][nt][r] + bv[r]);
                    *(bfx4*)&out[(size_t)pxv[nt] * 64 + mt * 16 + kg * 4] = o;
                }
            }
        }
    }
}

// ---------------- fused BN4+relu+avgpool5 + projection (block = image, no atomics)
__global__ void bnpool_proj_kernel(const bf16* buf4, const float* scsh,
                                   const float* gW1, float* A, float* Bq) {
    __shared__ float fs[576];
    int n = blockIdx.x;
    int g = n >= NSUP;
    int tid = threadIdx.x;
    for (int e = tid; e < 576; e += 256) {
        int c = e / 9, p9 = e % 9;
        float sc = scsh[g * 64 + c], sh = scsh[128 + g * 64 + c];
        int ii = p9 / 3, jj = p9 % 3;
        const bf16* base = buf4 + ((size_t)n * 225 + ii * 5 * 15 + jj * 5) * 64 + c;
        float s = 0;
        #pragma unroll
        for (int u = 0; u < 5; ++u)
            #pragma unroll
            for (int v = 0; v < 5; ++v)
                s += fmaxf(__bfloat162float(base[(u * 15 + v) * 64]) * sc + sh, 0.f);
        fs[e] = s * 0.04f;
    }
    __syncthreads();
    int k = tid;
    const float* W = g ? gW1 + 66 * 256 : gW1;
    float* out = g ? Bq + (size_t)(n - NSUP) * 9 * 256 : A + (size_t)n * 9 * 256;
    for (int p = 0; p < 9; ++p) {
        float acc = 0;
        for (int c = 0; c < 64; ++c) acc += fs[c * 9 + p] * W[c * 256 + k];
        acc += ((float)(p / 3) * (1.f / 3.f)) * W[64 * 256 + k];
        acc += ((float)(p % 3) * (1.f / 3.f)) * W[65 * 256 + k];
        out[p * 256 + k] = acc;
    }
}

// ---------------- H0 = relu(A + Bq + gb1), bf16, [GMP][256]
__global__ void h0_kernel(const float* A, const float* Bq, const float* gb1, bf16* H) {
    int tid = threadIdx.x;
    int row = blockIdx.x * 8 + (tid >> 5);
    int col = (tid & 31) * 8;
    short8 o;
    if (row < GM) {
        int bqs = row / 81, r81 = row % 81;
        int ps = r81 / 9, pq = r81 % 9;
        int b = bqs / 75, r75 = bqs % 75, q = r75 / 5, s = r75 % 5;
        const float* Ar = A + ((size_t)((b * 5 + s) * 9 + ps)) * 256 + col;
        const float* Br = Bq + ((size_t)((b * 15 + q) * 9 + pq)) * 256 + col;
        #pragma unroll
        for (int j = 0; j < 8; ++j) {
            float v = Ar[j] + Br[j] + gb1[col + j];
            o[j] = bfbits(fmaxf(v, 0.f));
        }
    } else {
        #pragma unroll
        for (int j = 0; j < 8; ++j) o[j] = 0;
    }
    *(short8*)&H[(size_t)row * 256 + col] = o;
}

// ---------------- generalized MFMA GEMM (double-buffered global_load_lds)
template <int KT, bool RELU, bool F32OUT>
__global__ __launch_bounds__(256) void gemm_f_kernel(
        const bf16* __restrict__ Ain, const bf16* __restrict__ WT,
        const float* __restrict__ bias, void* __restrict__ outv, int ldo) {
    constexpr int K = KT * 32;
    __shared__ __align__(16) short As[2][4096];
    __shared__ __align__(16) short Bs[2][4096];
    int bm0 = blockIdx.x * 128;
    int bn0 = blockIdx.y * 128;
    int tid = threadIdx.x, wv = tid >> 6, ln = tid & 63;
    int wm = wv >> 1, wn = wv & 1;

    int srow = (wv * 2) * 16 + (ln >> 2);
    int scol = (ln & 3) * 8;
    const bf16* Ag = Ain + (size_t)(bm0 + srow) * K + scol;
    const bf16* Bg = WT + (size_t)(bn0 + srow) * K + scol;

    f32x4 acc[4][4];
    #pragma unroll
    for (int m = 0; m < 4; ++m)
        #pragma unroll
        for (int n = 0; n < 4; ++n)
            #pragma unroll
            for (int r = 0; r < 4; ++r) acc[m][n][r] = 0.f;

    int ar = (wm * 64 + (ln & 15)) * 32 + (ln >> 4) * 8;
    int br = (wn * 64 + (ln & 15)) * 32 + (ln >> 4) * 8;

    GLL(Ag,          &As[0][(wv * 2) * 512]);
    GLL(Ag + 16 * K, &As[0][(wv * 2 + 1) * 512]);
    GLL(Bg,          &Bs[0][(wv * 2) * 512]);
    GLL(Bg + 16 * K, &Bs[0][(wv * 2 + 1) * 512]);
    __syncthreads();

    int cur = 0;
    for (int kt = 0; kt < KT; ++kt) {
        if (kt < KT - 1) {
            int k0 = (kt + 1) * 32;
            GLL(Ag + k0,          &As[cur ^ 1][(wv * 2) * 512]);
            GLL(Ag + 16 * K + k0, &As[cur ^ 1][(wv * 2 + 1) * 512]);
            GLL(Bg + k0,          &Bs[cur ^ 1][(wv * 2) * 512]);
            GLL(Bg + 16 * K + k0, &Bs[cur ^ 1][(wv * 2 + 1) * 512]);
        }
        short8 a[4], b[4];
        #pragma unroll
        for (int m = 0; m < 4; ++m) a[m] = *(const short8*)&As[cur][ar + m * 512];
        #pragma unroll
        for (int n = 0; n < 4; ++n) b[n] = *(const short8*)&Bs[cur][br + n * 512];
        #pragma unroll
        for (int m = 0; m < 4; ++m)
            #pragma unroll
            for (int n = 0; n < 4; ++n)
                acc[m][n] = __builtin_amdgcn_mfma_f32_16x16x32_bf16(a[m], b[n], acc[m][n], 0, 0, 0);
        __syncthreads();
        cur ^= 1;
    }

    int orow = bm0 + wm * 64 + (ln >> 4) * 4;
    int ocol = bn0 + wn * 64 + (ln & 15);
    #pragma unroll
    for (int n = 0; n < 4; ++n) {
        float bv = bias[ocol + n * 16];
        #pragma unroll
        for (int m = 0; m < 4; ++m) {
            #pragma unroll
            for (int r = 0; r < 4; ++r) {
                float v = acc[m][n][r] + bv;
                if (RELU) v = fmaxf(v, 0.f);
                size_t oi = (size_t)(orow + m * 16 + r) * ldo + ocol + n * 16;
                if (F32OUT) ((float*)outv)[oi] = v;
                else        ((bf16*)outv)[oi] = __float2bfloat16(v);
            }
        }
    }
}

// ---------------- xf (bf16, padded to 640 rows) = sum over 81 rows of H3, vectorized
__global__ void xfred_kernel(const bf16* H, bf16* xfb) {
    int bqs = blockIdx.x, tid = threadIdx.x;
    int sub = tid & 31, rl = tid >> 5;
    float s[8];
    #pragma unroll
    for (int j = 0; j < 8; ++j) s[j] = 0.f;
    if (bqs < 600) {
        const bf16* p = H + (size_t)bqs * 81 * 256 + sub * 8;
        for (int r = rl; r < 81; r += 8) {
            short8 v = *(const short8*)&p[r * 256];
            #pragma unroll
            for (int j = 0; j < 8; ++j) s[j] += b2f(v[j]);
        }
    }
    __shared__ float red[256][8];
    #pragma unroll
    for (int j = 0; j < 8; ++j) red[tid][j] = s[j];
    __syncthreads();
    if (tid < 32) {
        short8 o;
        #pragma unroll
        for (int j = 0; j < 8; ++j) {
            float t = 0;
            #pragma unroll
            for (int k = 0; k < 8; ++k) t += red[k * 32 + tid][j];
            o[j] = bfbits(t);
        }
        *(short8*)&xfb[(size_t)bqs * 256 + tid * 8] = o;
    }
}

// ---------------- score + loss partial: block = (b,q), wave = s
__global__ void score_kernel(const float* F4, const int* sy, const int* qy, float* lossp) {
    __shared__ float scs[8];
    int bid = blockIdx.x;
    int tid = threadIdx.x;
    int s = tid >> 6, k = tid & 63;
    float v = F4[(size_t)(bid * 5 + s) * 128 + k];
    float sum = v * v;
    #pragma unroll
    for (int m = 1; m < 64; m <<= 1) sum += __shfl_xor(sum, m);
    if (k == 0) scs[s] = sqrtf(sum);
    __syncthreads();
    if (tid == 0) {
        int b = bid / 15, q = bid % 15;
        float n2 = 0;
        for (int j = 0; j < 5; ++j) n2 += scs[j] * scs[j];
        float n = sqrtf(n2);
        float f = n / (1.f + n2);
        int qyv = qy[b * 15 + q];
        float sc[5]; bool ap[5]; float sap = 0;
        for (int j = 0; j < 5; ++j) {
            sc[j] = scs[j] * f;
            ap[j] = (sy[b * 5 + j] == qyv);
            if (ap[j]) sap += sc[j];
        }
        float lp = 0;
        for (int j = 0; j < 5; ++j)
            if (!ap[j]) lp += fmaxf(sc[j] - sap + 0.2f, 0.f);
        lossp[bid] = lp;
    }
}

__global__ void lreduce_kernel(const float* lossp, float* out) {
    __shared__ float r[128];
    int tid = threadIdx.x;
    r[tid] = (tid < NQRY) ? lossp[tid] : 0.f;
    __syncthreads();
    for (int off = 64; off; off >>= 1) {
        if (tid < off) r[tid] += r[tid + off];
        __syncthreads();
    }
    if (tid == 0) out[0] = r[0];
}

extern "C" void kernel_launch(void* const* d_in, const int* in_sizes, int n_in,
                              void* d_out, int out_size, void* d_ws, size_t ws_size,
                              hipStream_t stream) {
    const float* sx  = (const float*)d_in[0];
    const int*   syp = (const int*)d_in[1];
    const float* qx  = (const float*)d_in[2];
    const int*   qyp = (const int*)d_in[3];
    const float* cw1 = (const float*)d_in[4];  const float* cb1 = (const float*)d_in[5];
    const float* bg1 = (const float*)d_in[6];  const float* bb1 = (const float*)d_in[7];
    const float* cw2 = (const float*)d_in[8];  const float* cb2 = (const float*)d_in[9];
    const float* bg2 = (const float*)d_in[10]; const float* bb2 = (const float*)d_in[11];
    const float* cw3 = (const float*)d_in[12]; const float* cb3 = (const float*)d_in[13];
    const float* bg3 = (const float*)d_in[14]; const float* bb3 = (const float*)d_in[15];
    const float* cw4 = (const float*)d_in[16]; const float* cb4 = (const float*)d_in[17];
    const float* bg4 = (const float*)d_in[18]; const float* bb4 = (const float*)d_in[19];
    const float* gW1 = (const float*)d_in[20]; const float* gb1 = (const float*)d_in[21];
    const float* gW2 = (const float*)d_in[22]; const float* gb2 = (const float*)d_in[23];
    const float* gW3 = (const float*)d_in[24]; const float* gb3 = (const float*)d_in[25];
    const float* gW4 = (const float*)d_in[26]; const float* gb4 = (const float*)d_in[27];
    const float* fW1 = (const float*)d_in[28]; const float* fb1 = (const float*)d_in[29];
    const float* fW2 = (const float*)d_in[30]; const float* fb2 = (const float*)d_in[31];
    const float* fW3 = (const float*)d_in[32]; const float* fb3 = (const float*)d_in[33];
    const float* fW4 = (const float*)d_in[34]; const float* fb4 = (const float*)d_in[35];

    char* w = (char*)d_ws;
    size_t off = 0;
    bf16*  buf1  = (bf16*)(w + off); off += 34426880ull;  // [160][1681][64] bf16
    bf16*  hbuf  = (bf16*)(w + off); off += 31150080ull;  // H ping-pong region B
    bf16*  pbuf2 = (bf16*)(w + off); off += 7393280ull;   // [160][361][64] bf16
    bf16*  buf3  = (bf16*)(w + off); off += 5918720ull;   // [160][289][64] bf16
    bf16*  buf4  = (bf16*)(w + off); off += 4608000ull;   // [160][225][64] bf16
    float* Abuf  = (float*)(w + off); off += 368640ull;   // 40x9x256
    float* Bbuf  = (float*)(w + off); off += 1105920ull;  // 120x9x256
    bf16*  xfb   = (bf16*)(w + off); off += 327680ull;    // [640][256] bf16
    bf16*  F1    = (bf16*)(w + off); off += 327680ull;    // [640][256] bf16
    bf16*  F2    = (bf16*)(w + off); off += 327680ull;    // [640][256] bf16
    bf16*  F3    = (bf16*)(w + off); off += 163840ull;    // [640][128] bf16
    float* F4    = (float*)(w + off); off += 327680ull;   // [640][128] f32
    float* partial = (float*)(w + off); off += 262144ull; // 512 x 128 f32
    float* scsh  = (float*)(w + off); off += 4096ull;     // 4 stages x 256
    bf16*  imgN  = (bf16*)(w + off); off += 9031680ull;   // [160][84][84][4] bf16
    bf16*  Wc1   = (bf16*)(w + off); off += 8192ull;      // [64][64] bf16
    bf16*  Wp    = (bf16*)(w + off); off += 224256ull;    // 3 x 64 x 584 bf16
    bf16*  WTg   = (bf16*)(w + off); off += 393216ull;    // 3 x 256x256 bf16
    bf16*  fWT   = (bf16*)(w + off); off += 360448ull;    // f-chain weights bf16 [n][k]
    float* fb4p  = (float*)(w + off); off += 512ull;      // padded fb4 [128]
    float* lossp = (float*)(w + off); off += 512ull;

    float* scsh1 = scsh;        float* scsh2 = scsh + 256;
    float* scsh3 = scsh + 512;  float* scsh4 = scsh + 768;
    bf16* Wp2 = Wp;
    bf16* Wp3 = Wp + 64 * 584;
    bf16* Wp4 = Wp + 2 * 64 * 584;
    bf16* fWT1 = fWT;
    bf16* fWT2 = fWT + 65536;
    bf16* fWT3 = fWT + 131072;
    bf16* fWT4 = fWT + 163840;

    // H ping-pong reuses dead conv buffers
    bf16* Hb0 = buf1;            // 24.9 MB <= 34.4 MB
    bf16* Hb1 = hbuf;            // 24.9 MB <= 31.2 MB

    // fused prep: nhwc4 (1128960 elems) + weight prep (493184)
    prep_kernel<<<(1128960 + 493184 + 255) / 256, 256, 0, stream>>>(
        sx, qx, imgN, cw1, cw2, cw3, cw4, gW2, gW3, gW4,
        fW1, fW2, fW3, fW4, fb4, Wc1, Wp, WTg, fWT, fb4p);

    // stage 1
    conv1m_kernel<<<NIMG * 27, 256, 0, stream>>>(imgN, Wc1, cb1, buf1);
    stats_nhwc_kernel<<<NBS + NBQ, 256, 0, stream>>>(buf1, 1681, partial);
    bnfin_kernel<<<1, 1024, 0, stream>>>(partial, bg1, bb1, 1681, scsh1);
    bnrelu_nhwc_kernel<<<(2151680 + 255) / 256, 256, 0, stream>>>(buf1, scsh1, 1681, 2151680);

    // stage 2
    convmfma_kernel<41, 39, true, 4><<<dim3(903), 256, 0, stream>>>(buf1, Wp2, cb2, pbuf2, 903);
    stats_nhwc_kernel<<<NBS + NBQ, 256, 0, stream>>>(pbuf2, 361, partial);
    bnfin_kernel<<<1, 1024, 0, stream>>>(partial, bg2, bb2, 361, scsh2);
    bnrelu_nhwc_kernel<<<(462080 + 255) / 256, 256, 0, stream>>>(pbuf2, scsh2, 361, 462080);

    // stage 3
    convmfma_kernel<19, 17, false, 2><<<dim3(362), 256, 0, stream>>>(pbuf2, Wp3, cb3, buf3, 362);
    stats_nhwc_kernel<<<NBS + NBQ, 256, 0, stream>>>(buf3, 289, partial);
    bnfin_kernel<<<1, 1024, 0, stream>>>(partial, bg3, bb3, 289, scsh3);
    bnrelu_nhwc_kernel<<<(369920 + 255) / 256, 256, 0, stream>>>(buf3, scsh3, 289, 369920);

    // stage 4
    convmfma_kernel<17, 15, false, 2><<<dim3(282), 256, 0, stream>>>(buf3, Wp4, cb4, buf4, 282);
    stats_nhwc_kernel<<<NBS + NBQ, 256, 0, stream>>>(buf4, 225, partial);
    bnfin_kernel<<<1, 1024, 0, stream>>>(partial, bg4, bb4, 225, scsh4);
    bnpool_proj_kernel<<<NIMG, 256, 0, stream>>>(buf4, scsh4, gW1, Abuf, Bbuf);

    // g-MLP as split MFMA GEMM chain
    h0_kernel<<<GMP / 8, 256, 0, stream>>>(Abuf, Bbuf, gb1, Hb0);
    dim3 ggrid(GMP / 128, 2);
    gemm_f_kernel<8, true, false><<<ggrid, 256, 0, stream>>>(Hb0, WTg,          gb2, (void*)Hb1, 256);
    gemm_f_kernel<8, true, false><<<ggrid, 256, 0, stream>>>(Hb1, WTg + 65536,  gb3, (void*)Hb0, 256);
    gemm_f_kernel<8, true, false><<<ggrid, 256, 0, stream>>>(Hb0, WTg + 131072, gb4, (void*)Hb1, 256);
    xfred_kernel<<<640, 256, 0, stream>>>(Hb1, xfb);

    // f-chain as batched MFMA GEMMs
    gemm_f_kernel<8, true,  false><<<dim3(5, 2), 256, 0, stream>>>(xfb, fWT1, fb1,  (void*)F1, 256);
    gemm_f_kernel<8, true,  false><<<dim3(5, 2), 256, 0, stream>>>(F1,  fWT2, fb2,  (void*)F2, 256);
    gemm_f_kernel<8, true,  false><<<dim3(5, 1), 256, 0, stream>>>(F2,  fWT3, fb3,  (void*)F3, 128);
    gemm_f_kernel<4, false, true ><<<dim3(5, 1), 256, 0, stream>>>(F3,  fWT4, fb4p, (void*)F4, 128);

    score_kernel<<<NQRY, 320, 0, stream>>>(F4, syp, qyp, lossp);
    lreduce_kernel<<<1, 128, 0, stream>>>(lossp, (float*)d_out);
}

// Round 17
// 356.222 us; speedup vs baseline: 1.8201x; 1.0773x over previous
//
#include <hip/hip_runtime.h>
#include <hip/hip_bf16.h>

typedef __hip_bfloat16 bf16;
typedef __attribute__((ext_vector_type(8))) short short8;
typedef __attribute__((ext_vector_type(4))) short bfx4;
typedef __attribute__((ext_vector_type(4))) float f32x4;

#define DEV __device__ __forceinline__

static constexpr int NSUP = 40;    // B*N_WAY*K_SHOT
static constexpr int NQRY = 120;   // B*Q
static constexpr int NIMG = 160;
static constexpr int GM   = 48600; // 600 * 81 rows of the g-MLP
static constexpr int GMP  = 48640; // padded to 380*128
static constexpr int NBS  = 128;   // stats blocks for support group
static constexpr int NBQ  = 384;   // stats blocks for query group

DEV float b2f(short s) {
    union { unsigned int u; float f; } v; v.u = ((unsigned int)(unsigned short)s) << 16; return v.f;
}
DEV short bfbits(float v) {
    bf16 h = __float2bfloat16(v);
    union { bf16 b; short s; } u; u.b = h; return u.s;
}

// bijective XCD swizzle (m204)
DEV int xcd_swz(int b, int nwg) {
    int q = nwg >> 3, r = nwg & 7;
    int x = b & 7, i = b >> 3;
    return (x < r) ? x * (q + 1) + i : r * (q + 1) + (x - r) * q + i;
}

#define GLL(gp, lp) __builtin_amdgcn_global_load_lds( \
    (const __attribute__((address_space(1))) void*)(gp), \
    (__attribute__((address_space(3))) void*)(lp), 16, 0, 0)

// ---------------- fused prep: input->NHWC4 + all weight transforms
__global__ void prep_kernel(const float* sx, const float* qx, bf16* img,
                            const float* cw1, const float* cw2, const float* cw3,
                            const float* cw4, const float* gW2, const float* gW3,
                            const float* gW4, const float* fW1, const float* fW2,
                            const float* fW3, const float* fW4, const float* fb4,
                            bf16* Wc1, bf16* Wp, bf16* WTg, bf16* fWT, float* fb4p) {
    long gid = (long)blockIdx.x * 256 + threadIdx.x;
    if (gid < (long)NIMG * 7056) {
        int n = (int)(gid / 7056), p = (int)(gid % 7056);
        const float* im = ((n < NSUP) ? sx + (size_t)n * 3 * 7056
                                      : qx + (size_t)(n - NSUP) * 3 * 7056) + p;
        bfx4 o;
        o[0] = bfbits(im[0]);
        o[1] = bfbits(im[7056]);
        o[2] = bfbits(im[14112]);
        o[3] = 0;
        *(bfx4*)&img[gid * 4] = o;
        return;
    }
    int idx = (int)(gid - (long)NIMG * 7056);
    if (idx < 4096) {
        int oc = idx >> 6, k = idx & 63;
        int ky = k >> 4, r = k & 15;
        float v = 0.f;
        if (ky < 3 && r < 12) {
            int kx = r >> 2, ic = r & 3;
            if (ic < 3) v = cw1[oc * 27 + ic * 9 + ky * 3 + kx];
        }
        Wc1[idx] = __float2bfloat16(v);
        return;
    }
    idx -= 4096;
    if (idx < 3 * 64 * 584) {
        int L = idx / (64 * 584), r = idx % (64 * 584);
        int oc = r / 584, kk = r % 584;
        const float* src = (L == 0) ? cw2 : (L == 1) ? cw3 : cw4;
        float v = 0.f;
        if (kk < 576) {
            int ic = kk & 63, tap = kk >> 6;
            v = src[oc * 576 + ic * 9 + tap];
        }
        Wp[idx] = __float2bfloat16(v);
        return;
    }
    idx -= 3 * 64 * 584;
    if (idx < 3 * 65536) {
        int L = idx >> 16, r = idx & 65535, n = r >> 8, k = r & 255;
        const float* W = (L == 0) ? gW2 : (L == 1) ? gW3 : gW4;
        WTg[idx] = __float2bfloat16(W[k * 256 + n]);
        return;
    }
    idx -= 3 * 65536;
    if (idx < 65536) {
        int n = idx >> 8, k = idx & 255;
        fWT[idx] = __float2bfloat16(fW1[k * 256 + n]);
    } else if (idx < 131072) {
        int r = idx - 65536, n = r >> 8, k = r & 255;
        fWT[idx] = __float2bfloat16(fW2[k * 256 + n]);
    } else if (idx < 163840) {
        int r = idx - 131072, n = r >> 8, k = r & 255;
        fWT[idx] = __float2bfloat16(fW3[k * 128 + n]);
    } else if (idx < 180224) {
        int r = idx - 163840, n = r >> 7, k = r & 127;
        float v = (n < 64) ? fW4[k * 64 + n] : 0.f;
        fWT[idx] = __float2bfloat16(v);
    } else if (idx < 180352) {
        int i = idx - 180224;
        fb4p[i] = (i < 64) ? fb4[i] : 0.f;
    }
}

// ---------------- conv1 via MFMA + fused maxpool2 (XCD-swizzled flat grid)
__global__ __launch_bounds__(256) void conv1m_kernel(
        const bf16* __restrict__ img, const bf16* __restrict__ Wc1,
        const float* __restrict__ cb1, bf16* __restrict__ out) {
    int wid = xcd_swz(blockIdx.x, NIMG * 27);
    int n = wid / 27, chunk = wid % 27;
    int wv = threadIdx.x >> 6, ln = threadIdx.x & 63;
    int pr = ln & 15, kg = ln >> 4;
    int t0 = (chunk * 4 + wv) * 16;
    int t = t0 + pr;
    int tc = t < 1681 ? t : 1680;
    int pyt = tc / 41, pxt = tc % 41;
    const bf16* ib = img + (size_t)n * 28224;

    short8 wf[4][2];
    #pragma unroll
    for (int mt = 0; mt < 4; ++mt)
        #pragma unroll
        for (int h = 0; h < 2; ++h)
            wf[mt][h] = *(const short8*)&Wc1[(size_t)(mt * 16 + pr) * 64 + h * 32 + kg * 8];

    int r8 = (kg & 1) * 8;
    int kyb = kg >> 1;
    short8 pf[4][2];
    #pragma unroll
    for (int nt = 0; nt < 4; ++nt) {
        int py = 2 * pyt + (nt >> 1), px = 2 * pxt + (nt & 1);
        #pragma unroll
        for (int h = 0; h < 2; ++h) {
            int ky = h * 2 + kyb;
            short8 f = {0, 0, 0, 0, 0, 0, 0, 0};
            if (ky < 3) {
                const bf16* p = ib + ((py + ky) * 84 + px) * 4 + r8;
                if (r8 == 0) {
                    bfx4 a0 = *(const bfx4*)p, a1 = *(const bfx4*)(p + 4);
                    f[0] = a0[0]; f[1] = a0[1]; f[2] = a0[2]; f[3] = a0[3];
                    f[4] = a1[0]; f[5] = a1[1]; f[6] = a1[2]; f[7] = a1[3];
                } else {
                    bfx4 a0 = *(const bfx4*)p;
                    f[0] = a0[0]; f[1] = a0[1]; f[2] = a0[2]; f[3] = a0[3];
                }
            }
            pf[nt][h] = f;
        }
    }

    f32x4 acc[4][4];
    #pragma unroll
    for (int a = 0; a < 4; ++a)
        #pragma unroll
        for (int b = 0; b < 4; ++b)
            #pragma unroll
            for (int r = 0; r < 4; ++r) acc[a][b][r] = 0.f;

    #pragma unroll
    for (int h = 0; h < 2; ++h)
        #pragma unroll
        for (int mt = 0; mt < 4; ++mt)
            #pragma unroll
            for (int nt = 0; nt < 4; ++nt)
                acc[mt][nt] = __builtin_amdgcn_mfma_f32_16x16x32_bf16(
                    wf[mt][h], pf[nt][h], acc[mt][nt], 0, 0, 0);

    if (t < 1681) {
        bf16* ob = out + ((size_t)n * 1681 + t) * 64;
        #pragma unroll
        for (int mt = 0; mt < 4; ++mt) {
            f32x4 v = acc[mt][0];
            #pragma unroll
            for (int nt = 1; nt < 4; ++nt)
                #pragma unroll
                for (int r = 0; r < 4; ++r) v[r] = fmaxf(v[r], acc[mt][nt][r]);
            bfx4 o;
            #pragma unroll
            for (int r = 0; r < 4; ++r) o[r] = bfbits(v[r] + cb1[mt * 16 + kg * 4 + r]);
            *(bfx4*)&ob[mt * 16 + kg * 4] = o;
        }
    }
}

// ---------------- NHWC BN stats, vectorized short8
__global__ void stats_nhwc_kernel(const bf16* buf, int HW, float* partial) {
    int blk = blockIdx.x;
    bool qg = blk >= NBS;
    int b0 = qg ? blk - NBS : blk;
    int nb = qg ? NBQ : NBS;
    const bf16* base = buf + (qg ? (size_t)NSUP * HW * 64 : 0);
    long rows = (long)(qg ? NQRY : NSUP) * HW;
    int tid = threadIdx.x;
    int sub = tid & 7, rl = tid >> 3;
    float s1[8], s2[8];
    #pragma unroll
    for (int j = 0; j < 8; ++j) { s1[j] = 0.f; s2[j] = 0.f; }
    for (long r = (long)b0 * 32 + rl; r < rows; r += (long)nb * 32) {
        short8 v = *(const short8*)&base[r * 64 + sub * 8];
        #pragma unroll
        for (int j = 0; j < 8; ++j) { float f = b2f(v[j]); s1[j] += f; s2[j] += f * f; }
    }
    __shared__ float l1[256][8], l2[256][8];
    #pragma unroll
    for (int j = 0; j < 8; ++j) { l1[tid][j] = s1[j]; l2[tid][j] = s2[j]; }
    __syncthreads();
    if (tid < 64) {
        int su = tid >> 3, j = tid & 7;
        float a = 0.f, b = 0.f;
        for (int k = 0; k < 32; ++k) { a += l1[su + k * 8][j]; b += l2[su + k * 8][j]; }
        partial[blk * 128 + tid] = a;
        partial[blk * 128 + 64 + tid] = b;
    }
}

// ---------------- finalize (parallel, separate launch)
__global__ __launch_bounds__(1024) void bnfin_kernel(
        const float* partial, const float* gam, const float* bet,
        int HW, float* scsh) {
    int tid = threadIdx.x;
    int out = tid >> 3;
    int part = tid & 7;
    int g = out >> 6, c = out & 63;
    int b0 = g ? NBS : 0, nb = g ? NBQ : NBS;
    float s1 = 0.f, s2 = 0.f;
    for (int b = b0 + part; b < b0 + nb; b += 8) {
        s1 += partial[b * 128 + c];
        s2 += partial[b * 128 + 64 + c];
    }
    __shared__ float r1[1024], r2[1024];
    r1[tid] = s1; r2[tid] = s2;
    __syncthreads();
    if (part == 0) {
        #pragma unroll
        for (int j = 1; j < 8; ++j) { s1 += r1[tid + j]; s2 += r2[tid + j]; }
        float cnt = (float)((g ? NQRY : NSUP)) * (float)HW;
        float mean = s1 / cnt;
        float var = s2 / cnt - mean * mean;
        float istd = rsqrtf(var + 1e-5f);
        float sc = gam[c] * istd;
        scsh[out] = sc;
        scsh[128 + out] = bet[c] - mean * sc;
    }
}

// ---------------- BN apply + relu in place
__global__ void bnrelu_nhwc_kernel(bf16* buf, const float* scsh, int HW, int total8) {
    int idx = blockIdx.x * 256 + threadIdx.x;
    if (idx >= total8) return;
    size_t e0 = (size_t)idx * 8;
    int c0 = (int)(e0 & 63);
    int g = (int)(e0 / ((size_t)HW * 64)) >= NSUP ? 1 : 0;
    short8 v = *(short8*)&buf[e0];
    short8 o;
    #pragma unroll
    for (int j = 0; j < 8; ++j) {
        int c = c0 + j;
        float f = b2f(v[j]) * scsh[g * 64 + c] + scsh[128 + g * 64 + c];
        o[j] = bfbits(fmaxf(f, 0.f));
    }
    *(short8*)&buf[e0] = o;
}

// ---------------- MFMA implicit-GEMM 3x3 conv with explicit 1-step pf prefetch
template <int IW, int OW, bool POOL, int NT>
__global__ __launch_bounds__(256) void convmfma_kernel(
        const bf16* __restrict__ in, const bf16* __restrict__ Wp,
        const float* __restrict__ cb, bf16* __restrict__ out, int nwg) {
    constexpr int M  = OW * OW;
    constexpr int PW = OW / 2;
    constexpr int MP = POOL ? PW * PW : M;
    constexpr int T  = NIMG * MP;
    constexpr int NPF = POOL ? 4 : NT;

    int wid = xcd_swz(blockIdx.x, nwg);
    int wv = threadIdx.x >> 6, ln = threadIdx.x & 63;
    int pr = ln & 15, kg = ln >> 4;

    const bf16* pptr[NPF];
    int pxv[NPF];
    if (POOL) {
        int gp = (wid * 4 + wv) * 16 + pr;
        int gpc = gp < T ? gp : T - 1;
        pxv[0] = gp;
        int n = gpc / MP, pp = gpc % MP;
        int py = pp / PW, px = pp % PW;
        const bf16* ib = in + (size_t)n * (IW * IW * 64) + kg * 8;
        #pragma unroll
        for (int nt = 0; nt < 4; ++nt)
            pptr[nt] = ib + ((2 * py + (nt >> 1)) * IW + 2 * px + (nt & 1)) * 64;
    } else {
        #pragma unroll
        for (int nt = 0; nt < NT; ++nt) {
            int gp = (wid * 4 + wv) * (16 * NT) + nt * 16 + pr;
            int gpc = gp < T ? gp : T - 1;
            pxv[nt] = gp;
            int n = gpc / M, pix = gpc % M;
            int y = pix / OW, x = pix % OW;
            pptr[nt] = in + ((size_t)n * (IW * IW) + y * IW + x) * 64 + kg * 8;
        }
    }
    const bf16* wb = Wp + kg * 8;

    f32x4 acc[4][NPF];
    #pragma unroll
    for (int a = 0; a < 4; ++a)
        #pragma unroll
        for (int b = 0; b < NPF; ++b)
            #pragma unroll
            for (int r = 0; r < 4; ++r) acc[a][b][r] = 0.f;

    short8 pf_c[NPF];
    #pragma unroll
    for (int nt = 0; nt < NPF; ++nt) pf_c[nt] = *(const short8*)(pptr[nt]);
    #pragma unroll
    for (int s = 0; s < 18; ++s) {
        short8 pf_n[NPF];
        if (s < 17) {
            int s2 = s + 1, tap2 = s2 >> 1, h2 = s2 & 1;
            int off2 = ((tap2 / 3) * IW + (tap2 % 3)) * 64 + h2 * 32;
            #pragma unroll
            for (int nt = 0; nt < NPF; ++nt)
                pf_n[nt] = *(const short8*)(pptr[nt] + off2);
        }
        int wk = s * 32;
        short8 wf[4];
        #pragma unroll
        for (int mt = 0; mt < 4; ++mt)
            wf[mt] = *(const short8*)(wb + (size_t)(mt * 16 + pr) * 584 + wk);
        #pragma unroll
        for (int mt = 0; mt < 4; ++mt)
            #pragma unroll
            for (int nt = 0; nt < NPF; ++nt)
                acc[mt][nt] = __builtin_amdgcn_mfma_f32_16x16x32_bf16(
                    wf[mt], pf_c[nt], acc[mt][nt], 0, 0, 0);
        if (s < 17) {
            #pragma unroll
            for (int nt = 0; nt < NPF; ++nt) pf_c[nt] = pf_n[nt];
        }
    }

    if (POOL) {
        int gp = pxv[0];
        if (gp < T) {
            bf16* ob = out + (size_t)gp * 64;
            #pragma unroll
            for (int mt = 0; mt < 4; ++mt) {
                f32x4 v = acc[mt][0];
                #pragma unroll
                for (int nt = 1; nt < 4; ++nt)
                    #pragma unroll
                    for (int r = 0; r < 4; ++r) v[r] = fmaxf(v[r], acc[mt][nt][r]);
                bfx4 o;
                #pragma unroll
                for (int r = 0; r < 4; ++r) o[r] = bfbits(v[r] + cb[mt * 16 + kg * 4 + r]);
                *(bfx4*)&ob[mt * 16 + kg * 4] = o;
            }
        }
    } else {
        #pragma unroll
        for (int mt = 0; mt < 4; ++mt) {
            float bv[4];
            #pragma unroll
            for (int r = 0; r < 4; ++r) bv[r] = cb[mt * 16 + kg * 4 + r];
            #pragma unroll
            for (int nt = 0; nt < NPF; ++nt) {
                if (pxv[nt] < T) {
                    bfx4 o;
                    #pragma unroll
                    for (int r = 0; r < 4; ++r) o[r] = bfbits(acc[mt][nt][r] + bv[r]);
                    *(bfx4*)&out[(size_t)pxv[nt] * 64 + mt * 16 + kg * 4] = o;
                }
            }
        }
    }
}

// ---------------- BN4 apply + relu + avgpool5 -> feat[n][c][9] f32 (coalesced, wave per wid)
__global__ void bnpool_kernel(const bf16* buf4, const float* scsh, float* feat) {
    int wid = blockIdx.x * 4 + (threadIdx.x >> 6);
    int c = threadIdx.x & 63;
    if (wid >= 1440) return;
    int n = wid / 9, p9 = wid % 9;
    int g = n >= NSUP;
    float sc = scsh[g * 64 + c], sh = scsh[128 + g * 64 + c];
    int ii = p9 / 3, jj = p9 % 3;
    const bf16* base = buf4 + ((size_t)n * 225 + ii * 5 * 15 + jj * 5) * 64 + c;
    float s = 0;
    #pragma unroll
    for (int u = 0; u < 5; ++u)
        #pragma unroll
        for (int v = 0; v < 5; ++v)
            s += fmaxf(__bfloat162float(base[(u * 15 + v) * 64]) * sc + sh, 0.f);
    feat[n * 576 + c * 9 + p9] = s * 0.04f;
}

// ---------------- projection: A = sup66 @ Ws, Bq = qry66 @ Wq
__global__ void proj_kernel(const float* feat, const float* gW1, float* A, float* Bq) {
    int n = blockIdx.x, k = threadIdx.x;
    const float* W = (n < NSUP) ? gW1 : gW1 + 66 * 256;
    float* out = (n < NSUP) ? A + (size_t)n * 9 * 256 : Bq + (size_t)(n - NSUP) * 9 * 256;
    const float* fb = feat + n * 576;
    for (int p = 0; p < 9; ++p) {
        float acc = 0;
        for (int c = 0; c < 64; ++c) acc += fb[c * 9 + p] * W[c * 256 + k];
        acc += ((float)(p / 3) * (1.f / 3.f)) * W[64 * 256 + k];
        acc += ((float)(p % 3) * (1.f / 3.f)) * W[65 * 256 + k];
        out[p * 256 + k] = acc;
    }
}

// ---------------- H0 = relu(A + Bq + gb1), bf16, [GMP][256]
__global__ void h0_kernel(const float* A, const float* Bq, const float* gb1, bf16* H) {
    int tid = threadIdx.x;
    int row = blockIdx.x * 8 + (tid >> 5);
    int col = (tid & 31) * 8;
    short8 o;
    if (row < GM) {
        int bqs = row / 81, r81 = row % 81;
        int ps = r81 / 9, pq = r81 % 9;
        int b = bqs / 75, r75 = bqs % 75, q = r75 / 5, s = r75 % 5;
        const float* Ar = A + ((size_t)((b * 5 + s) * 9 + ps)) * 256 + col;
        const float* Br = Bq + ((size_t)((b * 15 + q) * 9 + pq)) * 256 + col;
        #pragma unroll
        for (int j = 0; j < 8; ++j) {
            float v = Ar[j] + Br[j] + gb1[col + j];
            o[j] = bfbits(fmaxf(v, 0.f));
        }
    } else {
        #pragma unroll
        for (int j = 0; j < 8; ++j) o[j] = 0;
    }
    *(short8*)&H[(size_t)row * 256 + col] = o;
}

// ---------------- generalized MFMA GEMM (double-buffered global_load_lds)
template <int KT, bool RELU, bool F32OUT>
__global__ __launch_bounds__(256) void gemm_f_kernel(
        const bf16* __restrict__ Ain, const bf16* __restrict__ WT,
        const float* __restrict__ bias, void* __restrict__ outv, int ldo) {
    constexpr int K = KT * 32;
    __shared__ __align__(16) short As[2][4096];
    __shared__ __align__(16) short Bs[2][4096];
    int bm0 = blockIdx.x * 128;
    int bn0 = blockIdx.y * 128;
    int tid = threadIdx.x, wv = tid >> 6, ln = tid & 63;
    int wm = wv >> 1, wn = wv & 1;

    int srow = (wv * 2) * 16 + (ln >> 2);
    int scol = (ln & 3) * 8;
    const bf16* Ag = Ain + (size_t)(bm0 + srow) * K + scol;
    const bf16* Bg = WT + (size_t)(bn0 + srow) * K + scol;

    f32x4 acc[4][4];
    #pragma unroll
    for (int m = 0; m < 4; ++m)
        #pragma unroll
        for (int n = 0; n < 4; ++n)
            #pragma unroll
            for (int r = 0; r < 4; ++r) acc[m][n][r] = 0.f;

    int ar = (wm * 64 + (ln & 15)) * 32 + (ln >> 4) * 8;
    int br = (wn * 64 + (ln & 15)) * 32 + (ln >> 4) * 8;

    GLL(Ag,          &As[0][(wv * 2) * 512]);
    GLL(Ag + 16 * K, &As[0][(wv * 2 + 1) * 512]);
    GLL(Bg,          &Bs[0][(wv * 2) * 512]);
    GLL(Bg + 16 * K, &Bs[0][(wv * 2 + 1) * 512]);
    __syncthreads();

    int cur = 0;
    for (int kt = 0; kt < KT; ++kt) {
        if (kt < KT - 1) {
            int k0 = (kt + 1) * 32;
            GLL(Ag + k0,          &As[cur ^ 1][(wv * 2) * 512]);
            GLL(Ag + 16 * K + k0, &As[cur ^ 1][(wv * 2 + 1) * 512]);
            GLL(Bg + k0,          &Bs[cur ^ 1][(wv * 2) * 512]);
            GLL(Bg + 16 * K + k0, &Bs[cur ^ 1][(wv * 2 + 1) * 512]);
        }
        short8 a[4], b[4];
        #pragma unroll
        for (int m = 0; m < 4; ++m) a[m] = *(const short8*)&As[cur][ar + m * 512];
        #pragma unroll
        for (int n = 0; n < 4; ++n) b[n] = *(const short8*)&Bs[cur][br + n * 512];
        #pragma unroll
        for (int m = 0; m < 4; ++m)
            #pragma unroll
            for (int n = 0; n < 4; ++n)
                acc[m][n] = __builtin_amdgcn_mfma_f32_16x16x32_bf16(a[m], b[n], acc[m][n], 0, 0, 0);
        __syncthreads();
        cur ^= 1;
    }

    int orow = bm0 + wm * 64 + (ln >> 4) * 4;
    int ocol = bn0 + wn * 64 + (ln & 15);
    #pragma unroll
    for (int n = 0; n < 4; ++n) {
        float bv = bias[ocol + n * 16];
        #pragma unroll
        for (int m = 0; m < 4; ++m) {
            #pragma unroll
            for (int r = 0; r < 4; ++r) {
                float v = acc[m][n][r] + bv;
                if (RELU) v = fmaxf(v, 0.f);
                size_t oi = (size_t)(orow + m * 16 + r) * ldo + ocol + n * 16;
                if (F32OUT) ((float*)outv)[oi] = v;
                else        ((bf16*)outv)[oi] = __float2bfloat16(v);
            }
        }
    }
}

// ---------------- xf (bf16, padded to 640 rows) = sum over 81 rows of H3, vectorized
__global__ void xfred_kernel(const bf16* H, bf16* xfb) {
    int bqs = blockIdx.x, tid = threadIdx.x;
    int sub = tid & 31, rl = tid >> 5;
    float s[8];
    #pragma unroll
    for (int j = 0; j < 8; ++j) s[j] = 0.f;
    if (bqs < 600) {
        const bf16* p = H + (size_t)bqs * 81 * 256 + sub * 8;
        for (int r = rl; r < 81; r += 8) {
            short8 v = *(const short8*)&p[r * 256];
            #pragma unroll
            for (int j = 0; j < 8; ++j) s[j] += b2f(v[j]);
        }
    }
    __shared__ float red[256][8];
    #pragma unroll
    for (int j = 0; j < 8; ++j) red[tid][j] = s[j];
    __syncthreads();
    if (tid < 32) {
        short8 o;
        #pragma unroll
        for (int j = 0; j < 8; ++j) {
            float t = 0;
            #pragma unroll
            for (int k = 0; k < 8; ++k) t += red[k * 32 + tid][j];
            o[j] = bfbits(t);
        }
        *(short8*)&xfb[(size_t)bqs * 256 + tid * 8] = o;
    }
}

// ---------------- score + loss partial: block = (b,q), wave = s
__global__ void score_kernel(const float* F4, const int* sy, const int* qy, float* lossp) {
    __shared__ float scs[8];
    int bid = blockIdx.x;
    int tid = threadIdx.x;
    int s = tid >> 6, k = tid & 63;
    float v = F4[(size_t)(bid * 5 + s) * 128 + k];
    float sum = v * v;
    #pragma unroll
    for (int m = 1; m < 64; m <<= 1) sum += __shfl_xor(sum, m);
    if (k == 0) scs[s] = sqrtf(sum);
    __syncthreads();
    if (tid == 0) {
        int b = bid / 15, q = bid % 15;
        float n2 = 0;
        for (int j = 0; j < 5; ++j) n2 += scs[j] * scs[j];
        float n = sqrtf(n2);
        float f = n / (1.f + n2);
        int qyv = qy[b * 15 + q];
        float sc[5]; bool ap[5]; float sap = 0;
        for (int j = 0; j < 5; ++j) {
            sc[j] = scs[j] * f;
            ap[j] = (sy[b * 5 + j] == qyv);
            if (ap[j]) sap += sc[j];
        }
        float lp = 0;
        for (int j = 0; j < 5; ++j)
            if (!ap[j]) lp += fmaxf(sc[j] - sap + 0.2f, 0.f);
        lossp[bid] = lp;
    }
}

__global__ void lreduce_kernel(const float* lossp, float* out) {
    __shared__ float r[128];
    int tid = threadIdx.x;
    r[tid] = (tid < NQRY) ? lossp[tid] : 0.f;
    __syncthreads();
    for (int off = 64; off; off >>= 1) {
        if (tid < off) r[tid] += r[tid + off];
        __syncthreads();
    }
    if (tid == 0) out[0] = r[0];
}

extern "C" void kernel_launch(void* const* d_in, const int* in_sizes, int n_in,
                              void* d_out, int out_size, void* d_ws, size_t ws_size,
                              hipStream_t stream) {
    const float* sx  = (const float*)d_in[0];
    const int*   syp = (const int*)d_in[1];
    const float* qx  = (const float*)d_in[2];
    const int*   qyp = (const int*)d_in[3];
    const float* cw1 = (const float*)d_in[4];  const float* cb1 = (const float*)d_in[5];
    const float* bg1 = (const float*)d_in[6];  const float* bb1 = (const float*)d_in[7];
    const float* cw2 = (const float*)d_in[8];  const float* cb2 = (const float*)d_in[9];
    const float* bg2 = (const float*)d_in[10]; const float* bb2 = (const float*)d_in[11];
    const float* cw3 = (const float*)d_in[12]; const float* cb3 = (const float*)d_in[13];
    const float* bg3 = (const float*)d_in[14]; const float* bb3 = (const float*)d_in[15];
    const float* cw4 = (const float*)d_in[16]; const float* cb4 = (const float*)d_in[17];
    const float* bg4 = (const float*)d_in[18]; const float* bb4 = (const float*)d_in[19];
    const float* gW1 = (const float*)d_in[20]; const float* gb1 = (const float*)d_in[21];
    const float* gW2 = (const float*)d_in[22]; const float* gb2 = (const float*)d_in[23];
    const float* gW3 = (const float*)d_in[24]; const float* gb3 = (const float*)d_in[25];
    const float* gW4 = (const float*)d_in[26]; const float* gb4 = (const float*)d_in[27];
    const float* fW1 = (const float*)d_in[28]; const float* fb1 = (const float*)d_in[29];
    const float* fW2 = (const float*)d_in[30]; const float* fb2 = (const float*)d_in[31];
    const float* fW3 = (const float*)d_in[32]; const float* fb3 = (const float*)d_in[33];
    const float* fW4 = (const float*)d_in[34]; const float* fb4 = (const float*)d_in[35];

    char* w = (char*)d_ws;
    size_t off = 0;
    bf16*  buf1  = (bf16*)(w + off); off += 34426880ull;  // [160][1681][64] bf16
    bf16*  hbuf  = (bf16*)(w + off); off += 31150080ull;  // H ping-pong region B
    bf16*  pbuf2 = (bf16*)(w + off); off += 7393280ull;   // [160][361][64] bf16
    bf16*  buf3  = (bf16*)(w + off); off += 5918720ull;   // [160][289][64] bf16
    bf16*  buf4  = (bf16*)(w + off); off += 4608000ull;   // [160][225][64] bf16
    float* feat  = (float*)(w + off); off += 368640ull;   // [160][64][9] f32
    float* Abuf  = (float*)(w + off); off += 368640ull;   // 40x9x256
    float* Bbuf  = (float*)(w + off); off += 1105920ull;  // 120x9x256
    bf16*  xfb   = (bf16*)(w + off); off += 327680ull;    // [640][256] bf16
    bf16*  F1    = (bf16*)(w + off); off += 327680ull;    // [640][256] bf16
    bf16*  F2    = (bf16*)(w + off); off += 327680ull;    // [640][256] bf16
    bf16*  F3    = (bf16*)(w + off); off += 163840ull;    // [640][128] bf16
    float* F4    = (float*)(w + off); off += 327680ull;   // [640][128] f32
    float* partial = (float*)(w + off); off += 262144ull; // 512 x 128 f32
    float* scsh  = (float*)(w + off); off += 4096ull;     // 4 stages x 256
    bf16*  imgN  = (bf16*)(w + off); off += 9031680ull;   // [160][84][84][4] bf16
    bf16*  Wc1   = (bf16*)(w + off); off += 8192ull;      // [64][64] bf16
    bf16*  Wp    = (bf16*)(w + off); off += 224256ull;    // 3 x 64 x 584 bf16
    bf16*  WTg   = (bf16*)(w + off); off += 393216ull;    // 3 x 256x256 bf16
    bf16*  fWT   = (bf16*)(w + off); off += 360448ull;    // f-chain weights bf16 [n][k]
    float* fb4p  = (float*)(w + off); off += 512ull;      // padded fb4 [128]
    float* lossp = (float*)(w + off); off += 512ull;

    float* scsh1 = scsh;        float* scsh2 = scsh + 256;
    float* scsh3 = scsh + 512;  float* scsh4 = scsh + 768;
    bf16* Wp2 = Wp;
    bf16* Wp3 = Wp + 64 * 584;
    bf16* Wp4 = Wp + 2 * 64 * 584;
    bf16* fWT1 = fWT;
    bf16* fWT2 = fWT + 65536;
    bf16* fWT3 = fWT + 131072;
    bf16* fWT4 = fWT + 163840;

    // H ping-pong reuses dead conv buffers
    bf16* Hb0 = buf1;            // 24.9 MB <= 34.4 MB
    bf16* Hb1 = hbuf;            // 24.9 MB <= 31.2 MB

    // fused prep: nhwc4 (1128960 elems) + weight prep (493184)
    prep_kernel<<<(1128960 + 493184 + 255) / 256, 256, 0, stream>>>(
        sx, qx, imgN, cw1, cw2, cw3, cw4, gW2, gW3, gW4,
        fW1, fW2, fW3, fW4, fb4, Wc1, Wp, WTg, fWT, fb4p);

    // stage 1
    conv1m_kernel<<<NIMG * 27, 256, 0, stream>>>(imgN, Wc1, cb1, buf1);
    stats_nhwc_kernel<<<NBS + NBQ, 256, 0, stream>>>(buf1, 1681, partial);
    bnfin_kernel<<<1, 1024, 0, stream>>>(partial, bg1, bb1, 1681, scsh1);
    bnrelu_nhwc_kernel<<<(2151680 + 255) / 256, 256, 0, stream>>>(buf1, scsh1, 1681, 2151680);

    // stage 2
    convmfma_kernel<41, 39, true, 4><<<dim3(903), 256, 0, stream>>>(buf1, Wp2, cb2, pbuf2, 903);
    stats_nhwc_kernel<<<NBS + NBQ, 256, 0, stream>>>(pbuf2, 361, partial);
    bnfin_kernel<<<1, 1024, 0, stream>>>(partial, bg2, bb2, 361, scsh2);
    bnrelu_nhwc_kernel<<<(462080 + 255) / 256, 256, 0, stream>>>(pbuf2, scsh2, 361, 462080);

    // stage 3
    convmfma_kernel<19, 17, false, 2><<<dim3(362), 256, 0, stream>>>(pbuf2, Wp3, cb3, buf3, 362);
    stats_nhwc_kernel<<<NBS + NBQ, 256, 0, stream>>>(buf3, 289, partial);
    bnfin_kernel<<<1, 1024, 0, stream>>>(partial, bg3, bb3, 289, scsh3);
    bnrelu_nhwc_kernel<<<(369920 + 255) / 256, 256, 0, stream>>>(buf3, scsh3, 289, 369920);

    // stage 4
    convmfma_kernel<17, 15, false, 2><<<dim3(282), 256, 0, stream>>>(buf3, Wp4, cb4, buf4, 282);
    stats_nhwc_kernel<<<NBS + NBQ, 256, 0, stream>>>(buf4, 225, partial);
    bnfin_kernel<<<1, 1024, 0, stream>>>(partial, bg4, bb4, 225, scsh4);
    bnpool_kernel<<<360, 256, 0, stream>>>(buf4, scsh4, feat);

    proj_kernel<<<NIMG, 256, 0, stream>>>(feat, gW1, Abuf, Bbuf);

    // g-MLP as split MFMA GEMM chain
    h0_kernel<<<GMP / 8, 256, 0, stream>>>(Abuf, Bbuf, gb1, Hb0);
    dim3 ggrid(GMP / 128, 2);
    gemm_f_kernel<8, true, false><<<ggrid, 256, 0, stream>>>(Hb0, WTg,          gb2, (void*)Hb1, 256);
    gemm_f_kernel<8, true, false><<<ggrid, 256, 0, stream>>>(Hb1, WTg + 65536,  gb3, (void*)Hb0, 256);
    gemm_f_kernel<8, true, false><<<ggrid, 256, 0, stream>>>(Hb0, WTg + 131072, gb4, (void*)Hb1, 256);
    xfred_kernel<<<640, 256, 0, stream>>>(Hb1, xfb);

    // f-chain as batched MFMA GEMMs
    gemm_f_kernel<8, true,  false><<<dim3(5, 2), 256, 0, stream>>>(xfb, fWT1, fb1,  (void*)F1, 256);
    gemm_f_kernel<8, true,  false><<<dim3(5, 2), 256, 0, stream>>>(F1,  fWT2, fb2,  (void*)F2, 256);
    gemm_f_kernel<8, true,  false><<<dim3(5, 1), 256, 0, stream>>>(F2,  fWT3, fb3,  (void*)F3, 128);
    gemm_f_kernel<4, false, true ><<<dim3(5, 1), 256, 0, stream>>>(F3,  fWT4, fb4p, (void*)F4, 128);

    score_kernel<<<NQRY, 320, 0, stream>>>(F4, syp, qyp, lossp);
    lreduce_kernel<<<1, 128, 0, stream>>>(lossp, (float*)d_out);
}